// Round 14
// baseline (4187.360 us; speedup 1.0000x reference)
//
#include <hip/hip_runtime.h>
#include <math.h>

// ---- problem constants ----
constexpr int B_   = 64;
constexpr int S_   = 197;
constexpr int D_   = 768;
constexpr int H_   = 12;
constexpr int FF_  = 3072;
constexpr int DEPTH_ = 12;
constexpr int NP_  = 196;
constexpr int M_   = B_ * S_;    // 12608
constexpr int MP_  = B_ * NP_;   // 12544
constexpr int MR   = 12800;      // 100*128 padded rows

typedef __attribute__((ext_vector_type(8))) short  bf16x8;
typedef __attribute__((ext_vector_type(4))) float  f32x4;
typedef unsigned short ushort_t;

__device__ __forceinline__ ushort_t f2bf(float x) {
    unsigned u = __builtin_bit_cast(unsigned, x);
    unsigned r = u + 0x7FFFu + ((u >> 16) & 1u);
    return (ushort_t)(r >> 16);
}

// fast GELU (tanh form): max abs dev from exact erf-GELU ~3e-3, fine for bf16
__device__ __forceinline__ float gelu_f(float v) {
    float y = 0.7978845608f * v + 0.0356774081f * (v * v * v);
    float e = __builtin_amdgcn_exp2f(2.88539008178f * y);    // e^(2y)
    float t = 1.0f - 2.0f * __builtin_amdgcn_rcpf(1.0f + e); // tanh(y)
    return 0.5f * v * (1.0f + t);
}

#define GLOAD_LDS16(g, l)                                                      \
    __builtin_amdgcn_global_load_lds(                                          \
        (const __attribute__((address_space(1))) void*)(g),                    \
        (__attribute__((address_space(3))) void*)(l), 16, 0, 0)

// ===== 128xBN MFMA GEMM, fine-phase + 3-slot ring, SINGLE barrier/slice (R14) =====
// C[M,N] = epi(A[M,K] @ Bt[N,K]^T + bias)   A,Bt bf16; acc f32.
// EPI: 0 = bf16 out, 1 = bf16 out + GELU, 2 = f32 out + residual, 3 = f32 out.
// BM=128. (BN=256, 8 waves): 72KB LDS. (BN=128, 4 waves): 48KB -> 3 blocks/CU.
// LDS slice layout row-major: byte = row*64 + (chunk ^ ((row>>1)&3))*16.
// Conflict-free both sides (R10: SQ_LDS_BANK_CONFLICT == 0, FETCH unchanged).
// Phase (ONE barrier per slice — R14):
//   8 ds_read_b128 (slice s) ; stage slice s+2 (slot (s-1)%3) ;
//   lgkmcnt(0) ; sched_barrier ; setprio(1) 16 MFMA setprio(0) ;
//   vmcnt(LV) [slice s+1 landed; s+2 in flight] ; barrier.
// Safety: WAR on slot s-1 — every wave's phase-(s-1) reads completed before
// its own lgkm(0), which precedes its barrier arrival; stages are issued only
// after that barrier. RAW on slot s — each wave's vmcnt(LV) in phase s-1
// drains its slice-s loads before the barrier. barrier1 of R13 was redundant.
// NOTE (R12 lesson): wide-N ops (QKV, fc1) stay BN=256/8-wave (A-panel L2 reuse).

template<int EPI, int BN, int NWAVE>
__global__ __launch_bounds__(NWAVE * 64, (NWAVE == 8) ? 4 : 3)
void mm_t(const ushort_t* __restrict__ A, const ushort_t* __restrict__ Bt,
          const float* __restrict__ bias, const float* __restrict__ res,
          void* __restrict__ Cout, int M, int N, int K) {
    constexpr int THREADS = NWAVE * 64;
    constexpr int SLICE   = (128 + BN) * 64;      // bytes per slice (A 8KB | B BN*64)
    constexpr int PASSB   = THREADS * 16;         // bytes staged per pass
    constexpr int PA      = 8192 / PASSB;         // A passes per slice
    constexpr int PB      = (BN * 64) / PASSB;    // B passes per slice
    constexpr int LV      = PA + PB;              // gload_lds per thread per slice
    __shared__ __align__(16) char lds[3 * SLICE];

    const int tid  = threadIdx.x;
    const int wid  = tid >> 6;
    const int lane = tid & 63;

    // bijective XCD-chunked swizzle (m204)
    const int nwg  = gridDim.x * gridDim.y;
    const int orig = blockIdx.y * gridDim.x + blockIdx.x;
    const int xcd  = orig & 7, slot = orig >> 3;
    const int q8   = nwg >> 3, r8 = nwg & 7;
    const int logical = (xcd < r8 ? xcd * (q8 + 1) : r8 * (q8 + 1) + (xcd - r8) * q8) + slot;
    const int m0 = (logical / gridDim.x) * 128;
    const int n0 = (logical % gridDim.x) * BN;

    const int wr  = (NWAVE == 8) ? (wid >> 2) : (wid >> 1);   // row half
    const int wcn = (NWAVE == 8) ? (wid & 3)  : (wid & 1);    // col group (64 cols)
    const int l15 = lane & 15, kq = lane >> 4;

    // read-side fragment byte offsets within a slice (R10 swizzle)
    const int chb   = ((kq ^ ((l15 >> 1) & 3)) & 3) * 16;
    const int abase = wr * 4096 + l15 * 64 + chb;            // + m*1024
    const int bbase = 8192 + wcn * 4096 + l15 * 64 + chb;    // + n*1024

    // stage-side: thread t covers row srow (+p*THREADS/4), chunk sc (pre-swizzled)
    const int srow = tid >> 2;
    const int sc   = (tid & 3) ^ ((tid >> 3) & 3);
    size_t gA[PA], gB[PB];
    #pragma unroll
    for (int p = 0; p < PA; ++p) gA[p] = (size_t)(m0 + srow + p * (THREADS / 4)) * K + sc * 8;
    #pragma unroll
    for (int p = 0; p < PB; ++p) gB[p] = (size_t)(n0 + srow + p * (THREADS / 4)) * K + sc * 8;

    f32x4 acc[4][4];
    #pragma unroll
    for (int m = 0; m < 4; ++m)
        #pragma unroll
        for (int n = 0; n < 4; ++n)
            acc[m][n] = (f32x4){0.f, 0.f, 0.f, 0.f};

#define MMT_STAGE(ss)                                                          \
    { char* d_ = lds + ((ss) % 3) * SLICE + wid * 1024;                        \
      const size_t ko_ = (size_t)(ss) * 32;                                    \
      _Pragma("unroll")                                                        \
      for (int p = 0; p < PA; ++p) GLOAD_LDS16(A + gA[p] + ko_, d_ + p * PASSB); \
      _Pragma("unroll")                                                        \
      for (int p = 0; p < PB; ++p) GLOAD_LDS16(Bt + gB[p] + ko_, d_ + 8192 + p * PASSB); }

#define MMT_VMW()                                                              \
    { if constexpr (LV == 3) { asm volatile("s_waitcnt vmcnt(3)" ::: "memory"); } \
      else                   { asm volatile("s_waitcnt vmcnt(4)" ::: "memory"); } }

#define MMT_PHASE(s_, DOSTAGE, FINAL)                                          \
  { const char* sb_ = lds + ((s_) % 3) * SLICE;                                \
    bf16x8 av[4], bv[4];                                                       \
    _Pragma("unroll")                                                          \
    for (int m = 0; m < 4; ++m) av[m] = *(const bf16x8*)(sb_ + abase + m * 1024); \
    _Pragma("unroll")                                                          \
    for (int n = 0; n < 4; ++n) bv[n] = *(const bf16x8*)(sb_ + bbase + n * 1024); \
    if (DOSTAGE) MMT_STAGE((s_) + 2);                                          \
    asm volatile("s_waitcnt lgkmcnt(0)" ::: "memory");                         \
    __builtin_amdgcn_sched_barrier(0);                                         \
    __builtin_amdgcn_s_setprio(1);                                             \
    _Pragma("unroll")                                                          \
    for (int m = 0; m < 4; ++m)                                                \
      _Pragma("unroll")                                                        \
      for (int n = 0; n < 4; ++n)                                              \
        acc[m][n] = __builtin_amdgcn_mfma_f32_16x16x32_bf16(av[m], bv[n], acc[m][n], 0, 0, 0); \
    __builtin_amdgcn_s_setprio(0);                                             \
    if (FINAL) { asm volatile("s_waitcnt vmcnt(0)" ::: "memory"); }            \
    else       { MMT_VMW(); }                                                  \
    __builtin_amdgcn_sched_barrier(0);                                         \
    __builtin_amdgcn_s_barrier(); }

    // prologue: slices 0,1 in flight; complete slice 0
    MMT_STAGE(0); MMT_STAGE(1);
    MMT_VMW();
    __builtin_amdgcn_s_barrier();

    const int NS = K >> 5;
    for (int s = 0; s < NS - 2; ++s) {
        MMT_PHASE(s, true, false);
    }
    MMT_PHASE(NS - 2, false, true);
    MMT_PHASE(NS - 1, false, true);

#undef MMT_STAGE
#undef MMT_VMW
#undef MMT_PHASE

    // epilogue: rows m0+wr*64+m*16+kq*4+j, cols n0+wcn*64+n*16+l15
    #pragma unroll
    for (int n = 0; n < 4; ++n) {
        const int col = n0 + wcn * 64 + n * 16 + l15;
        const float bcol = bias[col];
        #pragma unroll
        for (int m = 0; m < 4; ++m) {
            #pragma unroll
            for (int j = 0; j < 4; ++j) {
                const int row = m0 + wr * 64 + m * 16 + kq * 4 + j;
                float v = acc[m][n][j] + bcol;
                if (EPI == 1) v = gelu_f(v);
                if (EPI == 2) v += res[(size_t)row * N + col];
                if (EPI <= 1) ((ushort_t*)Cout)[(size_t)row * N + col] = f2bf(v);
                else          ((float*)Cout)[(size_t)row * N + col] = v;
            }
        }
    }
}

// ====================== MFMA attention ======================
constexpr int SKV = 224;     // padded KV length (7 k-tiles of 32)
constexpr int VLD = 232;     // padded Vt row length (elements)

__global__ __launch_bounds__(256)
void attn2_k(const ushort_t* __restrict__ qkv, ushort_t* __restrict__ o) {
    __shared__ __align__(16) ushort_t Ks[SKV * 64];   // [j][dh], XOR-swizzled
    __shared__ __align__(16) ushort_t Vt[64 * VLD];   // [dh][j], XOR-swizzled (R12)
    __shared__ __align__(16) ushort_t Pw[4 * 512];    // per-wave 16x32, swizzled
    const int h = blockIdx.x, b = blockIdx.y;
    const int tid = threadIdx.x, wid = tid >> 6, lane = tid & 63;
    const size_t baseq = (size_t)(b * S_) * 2304 + h * 64;
    char* const vtb = (char*)Vt;

    {
        const int jr  = tid >> 3;          // 0..31
        const int dh0 = (tid & 7) * 8;
        for (int pass = 0; pass < 7; ++pass) {
            const int j = pass * 32 + jr;
            bf16x8 kv = {0, 0, 0, 0, 0, 0, 0, 0};
            bf16x8 vv = {0, 0, 0, 0, 0, 0, 0, 0};
            if (j < S_) {
                kv = *(const bf16x8*)&qkv[baseq + (size_t)j * 2304 + 768  + dh0];
                vv = *(const bf16x8*)&qkv[baseq + (size_t)j * 2304 + 1536 + dh0];
            }
            const int koff = (j * 128 + dh0 * 2) ^ ((j & 7) << 4);
            *(bf16x8*)((char*)Ks + koff) = kv;
            #pragma unroll
            for (int i = 0; i < 8; ++i)
                *(ushort_t*)(vtb + ((((dh0 + i) * VLD + j) * 2) ^ ((tid & 7) << 4))) = (ushort_t)vv[i];
        }
    }
    __syncthreads();

    char* const pwb = (char*)Pw + wid * 1024;

    for (int it = 0; it < 4; ++it) {
        int sq = it * 64 + wid * 16 + (lane & 15);
        const int sqc = (sq < S_) ? sq : (S_ - 1);
        bf16x8 qf[2];
        #pragma unroll
        for (int kk = 0; kk < 2; ++kk)
            qf[kk] = *(const bf16x8*)&qkv[baseq + (size_t)sqc * 2304 + kk * 32 + (lane >> 4) * 8];

        f32x4 sa[14];
        #pragma unroll
        for (int nf = 0; nf < 14; ++nf) sa[nf] = (f32x4){0.f, 0.f, 0.f, 0.f};
        #pragma unroll
        for (int kk = 0; kk < 2; ++kk) {
            #pragma unroll
            for (int nf = 0; nf < 14; ++nf) {
                const int j = nf * 16 + (lane & 15);
                const int off = (j * 128 + kk * 64 + (lane >> 4) * 16) ^ ((j & 7) << 4);
                bf16x8 kf = *(const bf16x8*)((const char*)Ks + off);
                sa[nf] = __builtin_amdgcn_mfma_f32_16x16x32_bf16(qf[kk], kf, sa[nf], 0, 0, 0);
            }
        }

        const int jcol = lane & 15;
        float mx[4] = {-1e30f, -1e30f, -1e30f, -1e30f};
        #pragma unroll
        for (int nf = 0; nf < 14; ++nf)
            #pragma unroll
            for (int r = 0; r < 4; ++r) mx[r] = fmaxf(mx[r], sa[nf][r]);
        float ls[4];
        #pragma unroll
        for (int r = 0; r < 4; ++r) {
            float m = mx[r] * 0.125f;
            m = fmaxf(m, __shfl_xor(m, 1, 64));
            m = fmaxf(m, __shfl_xor(m, 2, 64));
            m = fmaxf(m, __shfl_xor(m, 4, 64));
            m = fmaxf(m, __shfl_xor(m, 8, 64));
            float s = 0.f;
            #pragma unroll
            for (int nf = 0; nf < 14; ++nf) {
                const int j = nf * 16 + jcol;
                float p = (j < S_) ? exp2f((sa[nf][r] * 0.125f - m) * 1.44269504088896f) : 0.f;
                sa[nf][r] = p;
                s += p;
            }
            s += __shfl_xor(s, 1, 64);
            s += __shfl_xor(s, 2, 64);
            s += __shfl_xor(s, 4, 64);
            s += __shfl_xor(s, 8, 64);
            ls[r] = s;
        }

        f32x4 oa[4];
        #pragma unroll
        for (int nf = 0; nf < 4; ++nf) oa[nf] = (f32x4){0.f, 0.f, 0.f, 0.f};
        #pragma unroll
        for (int kt = 0; kt < 7; ++kt) {
            #pragma unroll
            for (int half = 0; half < 2; ++half) {
                #pragma unroll
                for (int r = 0; r < 4; ++r) {
                    const int qr = (lane >> 4) * 4 + r;
                    const int jl = half * 16 + jcol;
                    const int off = (qr * 64 + jl * 2) ^ (((qr >> 1) & 3) << 4);
                    *(ushort_t*)(pwb + off) = f2bf(sa[kt * 2 + half][r]);
                }
            }
            const int arow = lane & 15;
            const int aoff2 = (arow * 64 + (lane >> 4) * 16) ^ (((arow >> 1) & 3) << 4);
            bf16x8 pa = *(const bf16x8*)(pwb + aoff2);
            #pragma unroll
            for (int nf = 0; nf < 4; ++nf) {
                const int dh = nf * 16 + (lane & 15);
                const int voff = ((dh * VLD + kt * 32 + (lane >> 4) * 8) * 2) ^ ((((nf * 2) + ((lane & 15) >> 3)) & 7) << 4);
                bf16x8 vb = *(const bf16x8*)(vtb + voff);
                oa[nf] = __builtin_amdgcn_mfma_f32_16x16x32_bf16(pa, vb, oa[nf], 0, 0, 0);
            }
        }

        #pragma unroll
        for (int r = 0; r < 4; ++r) {
            const int so = it * 64 + wid * 16 + (lane >> 4) * 4 + r;
            if (so < S_) {
                const float inv = 1.0f / ls[r];
                #pragma unroll
                for (int nf = 0; nf < 4; ++nf)
                    o[(size_t)(b * S_ + so) * 768 + h * 64 + nf * 16 + (lane & 15)] = f2bf(oa[nf][r] * inv);
            }
        }
    }
}

// ====================== small kernels ======================
__global__ __launch_bounds__(256)
void tcast_k(const float* __restrict__ in, ushort_t* __restrict__ out,
             int R, int C, size_t in_ls, size_t out_ls) {
    __shared__ float t[32][33];
    const float* ip = in + (size_t)blockIdx.z * in_ls;
    ushort_t* op = out + (size_t)blockIdx.z * out_ls;
    const int c0 = blockIdx.x * 32, r0 = blockIdx.y * 32;
    const int tx = threadIdx.x & 31, ty = threadIdx.x >> 5;
    #pragma unroll
    for (int i = 0; i < 4; ++i)
        t[ty + i * 8][tx] = ip[(size_t)(r0 + ty + i * 8) * C + c0 + tx];
    __syncthreads();
    #pragma unroll
    for (int i = 0; i < 4; ++i)
        op[(size_t)(c0 + ty + i * 8) * R + r0 + tx] = f2bf(t[tx][ty + i * 8]);
}

__global__ void cast_k(const float* __restrict__ in, ushort_t* __restrict__ out, int n) {
    int i = blockIdx.x * 256 + threadIdx.x;
    if (i < n) out[i] = f2bf(in[i]);
}

__global__ void biascat_k(const float* __restrict__ qb, const float* __restrict__ kb,
                          const float* __restrict__ vb, float* __restrict__ out) {
    int i = blockIdx.x * 256 + threadIdx.x;       // l*2304 + n
    if (i >= DEPTH_ * 2304) return;
    int l = i / 2304, n = i % 2304;
    float v = (n < 768) ? qb[l * 768 + n] : (n < 1536) ? kb[l * 768 + n - 768] : vb[l * 768 + n - 1536];
    out[i] = v;
}

__global__ void im2col_k(const float* __restrict__ x, ushort_t* __restrict__ pm) {
    size_t idx = (size_t)blockIdx.x * 256 + threadIdx.x;
    if (idx >= (size_t)MP_ * 768) return;
    int col = (int)(idx % 768);
    int row = (int)(idx / 768);
    int b = row / NP_, p = row % NP_;
    int c = col >> 8, rem = col & 255, ky = rem >> 4, kx = rem & 15;
    int py = p / 14, px = p % 14;
    pm[idx] = f2bf(x[(((size_t)b * 3 + c) * 224 + (py * 16 + ky)) * 224 + (px * 16 + kx)]);
}

__global__ void assemble_k(const float* __restrict__ pe, const float* __restrict__ cls,
                           const float* __restrict__ pos, float* __restrict__ h) {
    size_t idx = (size_t)blockIdx.x * 256 + threadIdx.x;
    if (idx >= (size_t)M_ * D_) return;
    int d = (int)(idx % D_);
    int row = (int)(idx / D_);
    int b = row / S_, s = row % S_;
    float v;
    if (s == 0) v = cls[d] + pos[d];
    else        v = pe[((size_t)b * NP_ + (s - 1)) * D_ + d] + pos[(size_t)s * D_ + d];
    h[idx] = v;
}

__device__ __forceinline__ float block_reduce_sum(float val) {
    __shared__ float sm[4];
    #pragma unroll
    for (int off = 32; off > 0; off >>= 1) val += __shfl_xor(val, off, 64);
    int wid = threadIdx.x >> 6;
    if ((threadIdx.x & 63) == 0) sm[wid] = val;
    __syncthreads();
    float r = (sm[0] + sm[1]) + (sm[2] + sm[3]);
    __syncthreads();
    return r;
}

template<bool BF16OUT>
__global__ __launch_bounds__(256)
void ln_k(const float* __restrict__ x, size_t xstride,
          void* __restrict__ y, size_t ystride,
          const float* __restrict__ s, const float* __restrict__ b) {
    const float* xr = x + (size_t)blockIdx.x * xstride;
    const int tid = threadIdx.x;
    float v[3];
    float sum = 0.f;
    #pragma unroll
    for (int t = 0; t < 3; ++t) { v[t] = xr[tid + t * 256]; sum += v[t]; }
    sum = block_reduce_sum(sum);
    const float mu = sum * (1.0f / 768.0f);
    float vs = 0.f;
    #pragma unroll
    for (int t = 0; t < 3; ++t) { float d = v[t] - mu; vs += d * d; }
    vs = block_reduce_sum(vs);
    const float rstd = rsqrtf(vs * (1.0f / 768.0f) + 1e-6f);
    #pragma unroll
    for (int t = 0; t < 3; ++t) {
        int c = tid + t * 256;
        float r = (v[t] - mu) * rstd * s[c] + b[c];
        if (BF16OUT) ((ushort_t*)y)[(size_t)blockIdx.x * ystride + c] = f2bf(r);
        else         ((float*)y)[(size_t)blockIdx.x * ystride + c] = r;
    }
}

// ====================== launch ======================
extern "C" void kernel_launch(void* const* d_in, const int* in_sizes, int n_in,
                              void* d_out, int out_size, void* d_ws, size_t ws_size,
                              hipStream_t stream) {
    const float* x       = (const float*)d_in[0];
    const float* patch_w = (const float*)d_in[1];
    const float* patch_b = (const float*)d_in[2];
    const float* cls_tok = (const float*)d_in[3];
    const float* pos_emb = (const float*)d_in[4];
    const float* ln1_s   = (const float*)d_in[5];
    const float* ln1_b   = (const float*)d_in[6];
    const float* qw      = (const float*)d_in[7];
    const float* qb      = (const float*)d_in[8];
    const float* kw      = (const float*)d_in[9];
    const float* kb      = (const float*)d_in[10];
    const float* vw      = (const float*)d_in[11];
    const float* vb      = (const float*)d_in[12];
    const float* pw      = (const float*)d_in[13];
    const float* pb      = (const float*)d_in[14];
    const float* ln2_s   = (const float*)d_in[15];
    const float* ln2_b   = (const float*)d_in[16];
    const float* fc1_w   = (const float*)d_in[17];
    const float* fc1_b   = (const float*)d_in[18];
    const float* fc2_w   = (const float*)d_in[19];
    const float* fc2_b   = (const float*)d_in[20];
    const float* lnf_s   = (const float*)d_in[21];
    const float* lnf_b   = (const float*)d_in[22];
    float* out = (float*)d_out;

    // ---- workspace layout (bytes) ----
    char* ws = (char*)d_ws;
    float*    h      = (float*)ws;                                   // MR*768 f32
    ushort_t* yb     = (ushort_t*)(ws + 39321600);                   // MR*768 bf16
    char*     Ubase  = ws + 58982400;                                 // shared region (MR*3072 bf16 max)
    ushort_t* qkvb   = (ushort_t*)Ubase;                              // MR*2304 bf16
    ushort_t* ub     = (ushort_t*)Ubase;                              // MR*3072 bf16
    float*    peb    = (float*)Ubase;                                 // MR*768 f32 (prologue)
    ushort_t* wqkv_t = (ushort_t*)(ws + 137625600);                   // 12*2304*768
    ushort_t* wp_t   = (ushort_t*)(ws + 180092928);                   // 12*768*768
    ushort_t* w1_t   = (ushort_t*)(ws + 194248704);                   // 12*3072*768
    ushort_t* w2_t   = (ushort_t*)(ws + 250871808);                   // 12*768*3072
    ushort_t* pwt    = (ushort_t*)(ws + 307494912);                   // 768*768
    float*    bqkv   = (float*)(ws + 308674560);                      // 12*2304 f32

    const dim3 blk(256);
    const dim3 blk512(512);

    // ---- weight prep ----
    tcast_k<<<dim3(768 / 32, 768 / 32, 12), blk, 0, stream>>>(qw, wqkv_t,            768, 768, (size_t)768 * 768, (size_t)2304 * 768);
    tcast_k<<<dim3(768 / 32, 768 / 32, 12), blk, 0, stream>>>(kw, wqkv_t + 768 * 768, 768, 768, (size_t)768 * 768, (size_t)2304 * 768);
    tcast_k<<<dim3(768 / 32, 768 / 32, 12), blk, 0, stream>>>(vw, wqkv_t + 1536 * 768, 768, 768, (size_t)768 * 768, (size_t)2304 * 768);
    tcast_k<<<dim3(768 / 32, 768 / 32, 12), blk, 0, stream>>>(pw, wp_t, 768, 768, (size_t)768 * 768, (size_t)768 * 768);
    tcast_k<<<dim3(3072 / 32, 768 / 32, 12), blk, 0, stream>>>(fc1_w, w1_t, 768, 3072, (size_t)768 * 3072, (size_t)3072 * 768);
    tcast_k<<<dim3(768 / 32, 3072 / 32, 12), blk, 0, stream>>>(fc2_w, w2_t, 3072, 768, (size_t)3072 * 768, (size_t)768 * 3072);
    cast_k<<<dim3((768 * 768 + 255) / 256), blk, 0, stream>>>(patch_w, pwt, 768 * 768);
    biascat_k<<<dim3((DEPTH_ * 2304 + 255) / 256), blk, 0, stream>>>(qb, kb, vb, bqkv);

    // ---- patch embed ----
    im2col_k<<<dim3(((size_t)MP_ * 768 + 255) / 256), blk, 0, stream>>>(x, yb);
    mm_t<3, 128, 4><<<dim3(6, 100), blk, 0, stream>>>(yb, pwt, patch_b, nullptr, peb, MR, 768, 768);
    assemble_k<<<dim3(((size_t)M_ * D_ + 255) / 256), blk, 0, stream>>>(peb, cls_tok, pos_emb, h);

    // ---- transformer blocks ----
    for (int l = 0; l < DEPTH_; ++l) {
        const size_t oDD = (size_t)l * 768 * 768;
        const size_t oD  = (size_t)l * 768;
        const size_t oDF = (size_t)l * 768 * FF_;
        const size_t oF  = (size_t)l * FF_;

        ln_k<true><<<dim3(M_), blk, 0, stream>>>(h, 768, yb, 768, ln1_s + oD, ln1_b + oD);
        mm_t<0, 256, 8><<<dim3(9, 100), blk512, 0, stream>>>(yb, wqkv_t + (size_t)l * 2304 * 768, bqkv + (size_t)l * 2304, nullptr, qkvb, MR, 2304, 768);
        attn2_k<<<dim3(H_, B_), blk, 0, stream>>>(qkvb, yb);
        mm_t<2, 128, 4><<<dim3(6, 100), blk, 0, stream>>>(yb, wp_t + oDD, pb + oD, h, h, MR, 768, 768);
        ln_k<true><<<dim3(M_), blk, 0, stream>>>(h, 768, yb, 768, ln2_s + oD, ln2_b + oD);
        mm_t<1, 256, 8><<<dim3(12, 100), blk512, 0, stream>>>(yb, w1_t + oDF, fc1_b + oF, nullptr, ub, MR, FF_, 768);
        mm_t<2, 128, 4><<<dim3(6, 100), blk, 0, stream>>>(ub, w2_t + oDF, fc2_b + oD, h, h, MR, 768, FF_);
    }

    // ---- final LN on CLS rows ----
    ln_k<false><<<dim3(B_), blk, 0, stream>>>(h, (size_t)S_ * D_, out, 768, lnf_s, lnf_b);
}

// Round 15
// 4081.869 us; speedup vs baseline: 1.0258x; 1.0258x over previous
//
#include <hip/hip_runtime.h>
#include <math.h>

// ---- problem constants ----
constexpr int B_   = 64;
constexpr int S_   = 197;
constexpr int D_   = 768;
constexpr int H_   = 12;
constexpr int FF_  = 3072;
constexpr int DEPTH_ = 12;
constexpr int NP_  = 196;
constexpr int M_   = B_ * S_;    // 12608
constexpr int MP_  = B_ * NP_;   // 12544
constexpr int MR   = 12800;      // 100*128 padded rows

typedef __attribute__((ext_vector_type(8))) short  bf16x8;
typedef __attribute__((ext_vector_type(4))) short  short4_t;
typedef __attribute__((ext_vector_type(4))) float  f32x4;
typedef unsigned short ushort_t;

__device__ __forceinline__ ushort_t f2bf(float x) {
    unsigned u = __builtin_bit_cast(unsigned, x);
    unsigned r = u + 0x7FFFu + ((u >> 16) & 1u);
    return (ushort_t)(r >> 16);
}

// fast GELU (tanh form): max abs dev from exact erf-GELU ~3e-3, fine for bf16
__device__ __forceinline__ float gelu_f(float v) {
    float y = 0.7978845608f * v + 0.0356774081f * (v * v * v);
    float e = __builtin_amdgcn_exp2f(2.88539008178f * y);    // e^(2y)
    float t = 1.0f - 2.0f * __builtin_amdgcn_rcpf(1.0f + e); // tanh(y)
    return 0.5f * v * (1.0f + t);
}

#define GLOAD_LDS16(g, l)                                                      \
    __builtin_amdgcn_global_load_lds(                                          \
        (const __attribute__((address_space(1))) void*)(g),                    \
        (__attribute__((address_space(3))) void*)(l), 16, 0, 0)

// ===== 128xBN MFMA GEMM, fine-phase + 3-slot ring (R10/R13-verified best) =====
// C[M,N] = epi(A[M,K] @ Bt[N,K]^T + bias)   A,Bt bf16; acc f32.
// EPI: 0 = bf16 out, 1 = bf16 out + GELU, 2 = f32 out + residual, 3 = f32 out.
// BM=128. (BN=256, 8 waves): 72KB LDS. (BN=128, 4 waves): 48KB -> 3 blocks/CU.
// LDS slice layout row-major: byte = row*64 + (chunk ^ ((row>>1)&3))*16.
// Conflict-free both sides (R10: SQ_LDS_BANK_CONFLICT == 0, FETCH unchanged).
// Per phase: 8 ds_read_b128 + stage slice s+2 -> barrier -> lgkmcnt(0) ->
// setprio(1) 16 MFMA -> counted vmcnt(LV) -> barrier. Never drain-0 mid-loop.
// NOTE (R12): wide-N ops (QKV, fc1) stay BN=256/8-wave (A-panel L2 reuse).
// NOTE (R14): single-barrier variant was neutral (within noise); keeping two.

template<int EPI, int BN, int NWAVE>
__global__ __launch_bounds__(NWAVE * 64, (NWAVE == 8) ? 4 : 3)
void mm_t(const ushort_t* __restrict__ A, const ushort_t* __restrict__ Bt,
          const float* __restrict__ bias, const float* __restrict__ res,
          void* __restrict__ Cout, int M, int N, int K) {
    constexpr int THREADS = NWAVE * 64;
    constexpr int SLICE   = (128 + BN) * 64;      // bytes per slice (A 8KB | B BN*64)
    constexpr int PASSB   = THREADS * 16;         // bytes staged per pass
    constexpr int PA      = 8192 / PASSB;         // A passes per slice
    constexpr int PB      = (BN * 64) / PASSB;    // B passes per slice
    constexpr int LV      = PA + PB;              // gload_lds per thread per slice
    __shared__ __align__(16) char lds[3 * SLICE];

    const int tid  = threadIdx.x;
    const int wid  = tid >> 6;
    const int lane = tid & 63;

    // bijective XCD-chunked swizzle (m204)
    const int nwg  = gridDim.x * gridDim.y;
    const int orig = blockIdx.y * gridDim.x + blockIdx.x;
    const int xcd  = orig & 7, slot = orig >> 3;
    const int q8   = nwg >> 3, r8 = nwg & 7;
    const int logical = (xcd < r8 ? xcd * (q8 + 1) : r8 * (q8 + 1) + (xcd - r8) * q8) + slot;
    const int m0 = (logical / gridDim.x) * 128;
    const int n0 = (logical % gridDim.x) * BN;

    const int wr  = (NWAVE == 8) ? (wid >> 2) : (wid >> 1);   // row half
    const int wcn = (NWAVE == 8) ? (wid & 3)  : (wid & 1);    // col group (64 cols)
    const int l15 = lane & 15, kq = lane >> 4;

    // read-side fragment byte offsets within a slice (R10 swizzle)
    const int chb   = ((kq ^ ((l15 >> 1) & 3)) & 3) * 16;
    const int abase = wr * 4096 + l15 * 64 + chb;            // + m*1024
    const int bbase = 8192 + wcn * 4096 + l15 * 64 + chb;    // + n*1024

    // stage-side: thread t covers row srow (+p*THREADS/4), chunk sc (pre-swizzled)
    const int srow = tid >> 2;
    const int sc   = (tid & 3) ^ ((tid >> 3) & 3);
    size_t gA[PA], gB[PB];
    #pragma unroll
    for (int p = 0; p < PA; ++p) gA[p] = (size_t)(m0 + srow + p * (THREADS / 4)) * K + sc * 8;
    #pragma unroll
    for (int p = 0; p < PB; ++p) gB[p] = (size_t)(n0 + srow + p * (THREADS / 4)) * K + sc * 8;

    f32x4 acc[4][4];
    #pragma unroll
    for (int m = 0; m < 4; ++m)
        #pragma unroll
        for (int n = 0; n < 4; ++n)
            acc[m][n] = (f32x4){0.f, 0.f, 0.f, 0.f};

#define MMT_STAGE(ss)                                                          \
    { char* d_ = lds + ((ss) % 3) * SLICE + wid * 1024;                        \
      const size_t ko_ = (size_t)(ss) * 32;                                    \
      _Pragma("unroll")                                                        \
      for (int p = 0; p < PA; ++p) GLOAD_LDS16(A + gA[p] + ko_, d_ + p * PASSB); \
      _Pragma("unroll")                                                        \
      for (int p = 0; p < PB; ++p) GLOAD_LDS16(Bt + gB[p] + ko_, d_ + 8192 + p * PASSB); }

#define MMT_VMW()                                                              \
    { if constexpr (LV == 3) { asm volatile("s_waitcnt vmcnt(3)" ::: "memory"); } \
      else                   { asm volatile("s_waitcnt vmcnt(4)" ::: "memory"); } }

#define MMT_PHASE(s_, DOSTAGE, FINAL)                                          \
  { const char* sb_ = lds + ((s_) % 3) * SLICE;                                \
    bf16x8 av[4], bv[4];                                                       \
    _Pragma("unroll")                                                          \
    for (int m = 0; m < 4; ++m) av[m] = *(const bf16x8*)(sb_ + abase + m * 1024); \
    _Pragma("unroll")                                                          \
    for (int n = 0; n < 4; ++n) bv[n] = *(const bf16x8*)(sb_ + bbase + n * 1024); \
    if (DOSTAGE) MMT_STAGE((s_) + 2);                                          \
    __builtin_amdgcn_sched_barrier(0);                                         \
    __builtin_amdgcn_s_barrier();                                              \
    asm volatile("s_waitcnt lgkmcnt(0)" ::: "memory");                         \
    __builtin_amdgcn_sched_barrier(0);                                         \
    __builtin_amdgcn_s_setprio(1);                                             \
    _Pragma("unroll")                                                          \
    for (int m = 0; m < 4; ++m)                                                \
      _Pragma("unroll")                                                        \
      for (int n = 0; n < 4; ++n)                                              \
        acc[m][n] = __builtin_amdgcn_mfma_f32_16x16x32_bf16(av[m], bv[n], acc[m][n], 0, 0, 0); \
    __builtin_amdgcn_s_setprio(0);                                             \
    if (FINAL) { asm volatile("s_waitcnt vmcnt(0)" ::: "memory"); }            \
    else       { MMT_VMW(); }                                                  \
    __builtin_amdgcn_sched_barrier(0);                                         \
    __builtin_amdgcn_s_barrier(); }

    // prologue: slices 0,1 in flight; complete slice 0
    MMT_STAGE(0); MMT_STAGE(1);
    MMT_VMW();
    __builtin_amdgcn_s_barrier();

    const int NS = K >> 5;
    for (int s = 0; s < NS - 2; ++s) {
        MMT_PHASE(s, true, false);
    }
    MMT_PHASE(NS - 2, false, true);
    MMT_PHASE(NS - 1, false, true);

#undef MMT_STAGE
#undef MMT_VMW
#undef MMT_PHASE

    // epilogue: rows m0+wr*64+m*16+kq*4+j, cols n0+wcn*64+n*16+l15
    #pragma unroll
    for (int n = 0; n < 4; ++n) {
        const int col = n0 + wcn * 64 + n * 16 + l15;
        const float bcol = bias[col];
        #pragma unroll
        for (int m = 0; m < 4; ++m) {
            #pragma unroll
            for (int j = 0; j < 4; ++j) {
                const int row = m0 + wr * 64 + m * 16 + kq * 4 + j;
                float v = acc[m][n][j] + bcol;
                if (EPI == 1) v = gelu_f(v);
                if (EPI == 2) v += res[(size_t)row * N + col];
                if (EPI <= 1) ((ushort_t*)Cout)[(size_t)row * N + col] = f2bf(v);
                else          ((float*)Cout)[(size_t)row * N + col] = v;
            }
        }
    }
}

// ====================== MFMA attention ======================
constexpr int SKV = 224;     // padded KV length (7 k-tiles of 32)
constexpr int VLD = 232;     // padded Vt row length (elements)

__global__ __launch_bounds__(256)
void attn2_k(const ushort_t* __restrict__ qkv, ushort_t* __restrict__ o) {
    __shared__ __align__(16) ushort_t Ks[SKV * 64];   // [j][dh], XOR-swizzled
    __shared__ __align__(16) ushort_t Vt[64 * VLD];   // [dh][j], XOR-swizzled (R12)
    __shared__ __align__(16) ushort_t Pw[4 * 512];    // per-wave 16x32, swizzled
    const int h = blockIdx.x, b = blockIdx.y;
    const int tid = threadIdx.x, wid = tid >> 6, lane = tid & 63;
    const size_t baseq = (size_t)(b * S_) * 2304 + h * 64;
    char* const vtb = (char*)Vt;

    {
        const int jr  = tid >> 3;          // 0..31
        const int dh0 = (tid & 7) * 8;
        for (int pass = 0; pass < 7; ++pass) {
            const int j = pass * 32 + jr;
            bf16x8 kv = {0, 0, 0, 0, 0, 0, 0, 0};
            bf16x8 vv = {0, 0, 0, 0, 0, 0, 0, 0};
            if (j < S_) {
                kv = *(const bf16x8*)&qkv[baseq + (size_t)j * 2304 + 768  + dh0];
                vv = *(const bf16x8*)&qkv[baseq + (size_t)j * 2304 + 1536 + dh0];
            }
            const int koff = (j * 128 + dh0 * 2) ^ ((j & 7) << 4);
            *(bf16x8*)((char*)Ks + koff) = kv;
            #pragma unroll
            for (int i = 0; i < 8; ++i)
                *(ushort_t*)(vtb + ((((dh0 + i) * VLD + j) * 2) ^ ((tid & 7) << 4))) = (ushort_t)vv[i];
        }
    }
    __syncthreads();

    char* const pwb = (char*)Pw + wid * 1024;

    for (int it = 0; it < 4; ++it) {
        int sq = it * 64 + wid * 16 + (lane & 15);
        const int sqc = (sq < S_) ? sq : (S_ - 1);
        bf16x8 qf[2];
        #pragma unroll
        for (int kk = 0; kk < 2; ++kk)
            qf[kk] = *(const bf16x8*)&qkv[baseq + (size_t)sqc * 2304 + kk * 32 + (lane >> 4) * 8];

        f32x4 sa[14];
        #pragma unroll
        for (int nf = 0; nf < 14; ++nf) sa[nf] = (f32x4){0.f, 0.f, 0.f, 0.f};
        #pragma unroll
        for (int kk = 0; kk < 2; ++kk) {
            #pragma unroll
            for (int nf = 0; nf < 14; ++nf) {
                const int j = nf * 16 + (lane & 15);
                const int off = (j * 128 + kk * 64 + (lane >> 4) * 16) ^ ((j & 7) << 4);
                bf16x8 kf = *(const bf16x8*)((const char*)Ks + off);
                sa[nf] = __builtin_amdgcn_mfma_f32_16x16x32_bf16(qf[kk], kf, sa[nf], 0, 0, 0);
            }
        }

        const int jcol = lane & 15;
        float mx[4] = {-1e30f, -1e30f, -1e30f, -1e30f};
        #pragma unroll
        for (int nf = 0; nf < 14; ++nf)
            #pragma unroll
            for (int r = 0; r < 4; ++r) mx[r] = fmaxf(mx[r], sa[nf][r]);
        float ls[4];
        #pragma unroll
        for (int r = 0; r < 4; ++r) {
            float m = mx[r] * 0.125f;
            m = fmaxf(m, __shfl_xor(m, 1, 64));
            m = fmaxf(m, __shfl_xor(m, 2, 64));
            m = fmaxf(m, __shfl_xor(m, 4, 64));
            m = fmaxf(m, __shfl_xor(m, 8, 64));
            float s = 0.f;
            #pragma unroll
            for (int nf = 0; nf < 14; ++nf) {
                const int j = nf * 16 + jcol;
                float p = (j < S_) ? exp2f((sa[nf][r] * 0.125f - m) * 1.44269504088896f) : 0.f;
                sa[nf][r] = p;
                s += p;
            }
            s += __shfl_xor(s, 1, 64);
            s += __shfl_xor(s, 2, 64);
            s += __shfl_xor(s, 4, 64);
            s += __shfl_xor(s, 8, 64);
            ls[r] = s;
        }

        f32x4 oa[4];
        #pragma unroll
        for (int nf = 0; nf < 4; ++nf) oa[nf] = (f32x4){0.f, 0.f, 0.f, 0.f};
        #pragma unroll
        for (int kt = 0; kt < 7; ++kt) {
            #pragma unroll
            for (int half = 0; half < 2; ++half) {
                #pragma unroll
                for (int r = 0; r < 4; ++r) {
                    const int qr = (lane >> 4) * 4 + r;
                    const int jl = half * 16 + jcol;
                    const int off = (qr * 64 + jl * 2) ^ (((qr >> 1) & 3) << 4);
                    *(ushort_t*)(pwb + off) = f2bf(sa[kt * 2 + half][r]);
                }
            }
            const int arow = lane & 15;
            const int aoff2 = (arow * 64 + (lane >> 4) * 16) ^ (((arow >> 1) & 3) << 4);
            bf16x8 pa = *(const bf16x8*)(pwb + aoff2);
            #pragma unroll
            for (int nf = 0; nf < 4; ++nf) {
                const int dh = nf * 16 + (lane & 15);
                const int voff = ((dh * VLD + kt * 32 + (lane >> 4) * 8) * 2) ^ ((((nf * 2) + ((lane & 15) >> 3)) & 7) << 4);
                bf16x8 vb = *(const bf16x8*)(vtb + voff);
                oa[nf] = __builtin_amdgcn_mfma_f32_16x16x32_bf16(pa, vb, oa[nf], 0, 0, 0);
            }
        }

        #pragma unroll
        for (int r = 0; r < 4; ++r) {
            const int so = it * 64 + wid * 16 + (lane >> 4) * 4 + r;
            if (so < S_) {
                const float inv = 1.0f / ls[r];
                #pragma unroll
                for (int nf = 0; nf < 4; ++nf)
                    o[(size_t)(b * S_ + so) * 768 + h * 64 + nf * 16 + (lane & 15)] = f2bf(oa[nf][r] * inv);
            }
        }
    }
}

// ====================== small kernels ======================
__global__ __launch_bounds__(256)
void tcast_k(const float* __restrict__ in, ushort_t* __restrict__ out,
             int R, int C, size_t in_ls, size_t out_ls) {
    __shared__ float t[32][33];
    const float* ip = in + (size_t)blockIdx.z * in_ls;
    ushort_t* op = out + (size_t)blockIdx.z * out_ls;
    const int c0 = blockIdx.x * 32, r0 = blockIdx.y * 32;
    const int tx = threadIdx.x & 31, ty = threadIdx.x >> 5;
    #pragma unroll
    for (int i = 0; i < 4; ++i)
        t[ty + i * 8][tx] = ip[(size_t)(r0 + ty + i * 8) * C + c0 + tx];
    __syncthreads();
    #pragma unroll
    for (int i = 0; i < 4; ++i)
        op[(size_t)(c0 + ty + i * 8) * R + r0 + tx] = f2bf(t[tx][ty + i * 8]);
}

__global__ void cast_k(const float* __restrict__ in, ushort_t* __restrict__ out, int n) {
    int i = blockIdx.x * 256 + threadIdx.x;
    if (i < n) out[i] = f2bf(in[i]);
}

__global__ void biascat_k(const float* __restrict__ qb, const float* __restrict__ kb,
                          const float* __restrict__ vb, float* __restrict__ out) {
    int i = blockIdx.x * 256 + threadIdx.x;       // l*2304 + n
    if (i >= DEPTH_ * 2304) return;
    int l = i / 2304, n = i % 2304;
    float v = (n < 768) ? qb[l * 768 + n] : (n < 1536) ? kb[l * 768 + n - 768] : vb[l * 768 + n - 1536];
    out[i] = v;
}

__global__ void im2col_k(const float* __restrict__ x, ushort_t* __restrict__ pm) {
    size_t idx = (size_t)blockIdx.x * 256 + threadIdx.x;
    if (idx >= (size_t)MP_ * 768) return;
    int col = (int)(idx % 768);
    int row = (int)(idx / 768);
    int b = row / NP_, p = row % NP_;
    int c = col >> 8, rem = col & 255, ky = rem >> 4, kx = rem & 15;
    int py = p / 14, px = p % 14;
    pm[idx] = f2bf(x[(((size_t)b * 3 + c) * 224 + (py * 16 + ky)) * 224 + (px * 16 + kx)]);
}

__global__ void assemble_k(const float* __restrict__ pe, const float* __restrict__ cls,
                           const float* __restrict__ pos, float* __restrict__ h) {
    size_t idx = (size_t)blockIdx.x * 256 + threadIdx.x;
    if (idx >= (size_t)M_ * D_) return;
    int d = (int)(idx % D_);
    int row = (int)(idx / D_);
    int b = row / S_, s = row % S_;
    float v;
    if (s == 0) v = cls[d] + pos[d];
    else        v = pe[((size_t)b * NP_ + (s - 1)) * D_ + d] + pos[(size_t)s * D_ + d];
    h[idx] = v;
}

// ======= vectorized LayerNorm: 4 rows/block, one wave per row (R15) =======
// float4 loads (16B/lane, G13), pure shuffle reduce — no LDS, no barriers.
template<bool BF16OUT>
__global__ __launch_bounds__(256)
void ln4_k(const float* __restrict__ x, size_t xstride,
           void* __restrict__ y, size_t ystride,
           const float* __restrict__ s, const float* __restrict__ b, int nrows) {
    const int wid = threadIdx.x >> 6, lane = threadIdx.x & 63;
    const int row = blockIdx.x * 4 + wid;
    if (row >= nrows) return;
    const float* xr = x + (size_t)row * xstride;

    f32x4 v[3];
    float sum = 0.f;
    #pragma unroll
    for (int t = 0; t < 3; ++t) {
        v[t] = *(const f32x4*)&xr[lane * 4 + t * 256];
        sum += (v[t][0] + v[t][1]) + (v[t][2] + v[t][3]);
    }
    #pragma unroll
    for (int off = 32; off > 0; off >>= 1) sum += __shfl_xor(sum, off, 64);
    const float mu = sum * (1.0f / 768.0f);

    float vs = 0.f;
    #pragma unroll
    for (int t = 0; t < 3; ++t)
        #pragma unroll
        for (int e = 0; e < 4; ++e) { float d = v[t][e] - mu; vs += d * d; }
    #pragma unroll
    for (int off = 32; off > 0; off >>= 1) vs += __shfl_xor(vs, off, 64);
    const float rstd = rsqrtf(vs * (1.0f / 768.0f) + 1e-6f);

    #pragma unroll
    for (int t = 0; t < 3; ++t) {
        const int c = lane * 4 + t * 256;
        const f32x4 sv = *(const f32x4*)&s[c];
        const f32x4 bv = *(const f32x4*)&b[c];
        if (BF16OUT) {
            short4_t o4;
            #pragma unroll
            for (int e = 0; e < 4; ++e)
                o4[e] = (short)f2bf((v[t][e] - mu) * rstd * sv[e] + bv[e]);
            *(short4_t*)((ushort_t*)y + (size_t)row * ystride + c) = o4;
        } else {
            f32x4 o;
            #pragma unroll
            for (int e = 0; e < 4; ++e)
                o[e] = (v[t][e] - mu) * rstd * sv[e] + bv[e];
            *(f32x4*)((float*)y + (size_t)row * ystride + c) = o;
        }
    }
}

// ====================== launch ======================
extern "C" void kernel_launch(void* const* d_in, const int* in_sizes, int n_in,
                              void* d_out, int out_size, void* d_ws, size_t ws_size,
                              hipStream_t stream) {
    const float* x       = (const float*)d_in[0];
    const float* patch_w = (const float*)d_in[1];
    const float* patch_b = (const float*)d_in[2];
    const float* cls_tok = (const float*)d_in[3];
    const float* pos_emb = (const float*)d_in[4];
    const float* ln1_s   = (const float*)d_in[5];
    const float* ln1_b   = (const float*)d_in[6];
    const float* qw      = (const float*)d_in[7];
    const float* qb      = (const float*)d_in[8];
    const float* kw      = (const float*)d_in[9];
    const float* kb      = (const float*)d_in[10];
    const float* vw      = (const float*)d_in[11];
    const float* vb      = (const float*)d_in[12];
    const float* pw      = (const float*)d_in[13];
    const float* pb      = (const float*)d_in[14];
    const float* ln2_s   = (const float*)d_in[15];
    const float* ln2_b   = (const float*)d_in[16];
    const float* fc1_w   = (const float*)d_in[17];
    const float* fc1_b   = (const float*)d_in[18];
    const float* fc2_w   = (const float*)d_in[19];
    const float* fc2_b   = (const float*)d_in[20];
    const float* lnf_s   = (const float*)d_in[21];
    const float* lnf_b   = (const float*)d_in[22];
    float* out = (float*)d_out;

    // ---- workspace layout (bytes) ----
    char* ws = (char*)d_ws;
    float*    h      = (float*)ws;                                   // MR*768 f32
    ushort_t* yb     = (ushort_t*)(ws + 39321600);                   // MR*768 bf16
    char*     Ubase  = ws + 58982400;                                 // shared region (MR*3072 bf16 max)
    ushort_t* qkvb   = (ushort_t*)Ubase;                              // MR*2304 bf16
    ushort_t* ub     = (ushort_t*)Ubase;                              // MR*3072 bf16
    float*    peb    = (float*)Ubase;                                 // MR*768 f32 (prologue)
    ushort_t* wqkv_t = (ushort_t*)(ws + 137625600);                   // 12*2304*768
    ushort_t* wp_t   = (ushort_t*)(ws + 180092928);                   // 12*768*768
    ushort_t* w1_t   = (ushort_t*)(ws + 194248704);                   // 12*3072*768
    ushort_t* w2_t   = (ushort_t*)(ws + 250871808);                   // 12*768*3072
    ushort_t* pwt    = (ushort_t*)(ws + 307494912);                   // 768*768
    float*    bqkv   = (float*)(ws + 308674560);                      // 12*2304 f32

    const dim3 blk(256);
    const dim3 blk512(512);

    // ---- weight prep ----
    tcast_k<<<dim3(768 / 32, 768 / 32, 12), blk, 0, stream>>>(qw, wqkv_t,            768, 768, (size_t)768 * 768, (size_t)2304 * 768);
    tcast_k<<<dim3(768 / 32, 768 / 32, 12), blk, 0, stream>>>(kw, wqkv_t + 768 * 768, 768, 768, (size_t)768 * 768, (size_t)2304 * 768);
    tcast_k<<<dim3(768 / 32, 768 / 32, 12), blk, 0, stream>>>(vw, wqkv_t + 1536 * 768, 768, 768, (size_t)768 * 768, (size_t)2304 * 768);
    tcast_k<<<dim3(768 / 32, 768 / 32, 12), blk, 0, stream>>>(pw, wp_t, 768, 768, (size_t)768 * 768, (size_t)768 * 768);
    tcast_k<<<dim3(3072 / 32, 768 / 32, 12), blk, 0, stream>>>(fc1_w, w1_t, 768, 3072, (size_t)768 * 3072, (size_t)3072 * 768);
    tcast_k<<<dim3(768 / 32, 3072 / 32, 12), blk, 0, stream>>>(fc2_w, w2_t, 3072, 768, (size_t)3072 * 768, (size_t)768 * 3072);
    cast_k<<<dim3((768 * 768 + 255) / 256), blk, 0, stream>>>(patch_w, pwt, 768 * 768);
    biascat_k<<<dim3((DEPTH_ * 2304 + 255) / 256), blk, 0, stream>>>(qb, kb, vb, bqkv);

    // ---- patch embed ----
    im2col_k<<<dim3(((size_t)MP_ * 768 + 255) / 256), blk, 0, stream>>>(x, yb);
    mm_t<3, 128, 4><<<dim3(6, 100), blk, 0, stream>>>(yb, pwt, patch_b, nullptr, peb, MR, 768, 768);
    assemble_k<<<dim3(((size_t)M_ * D_ + 255) / 256), blk, 0, stream>>>(peb, cls_tok, pos_emb, h);

    // ---- transformer blocks ----
    for (int l = 0; l < DEPTH_; ++l) {
        const size_t oDD = (size_t)l * 768 * 768;
        const size_t oD  = (size_t)l * 768;
        const size_t oDF = (size_t)l * 768 * FF_;
        const size_t oF  = (size_t)l * FF_;

        ln4_k<true><<<dim3(M_ / 4), blk, 0, stream>>>(h, 768, yb, 768, ln1_s + oD, ln1_b + oD, M_);
        mm_t<0, 256, 8><<<dim3(9, 100), blk512, 0, stream>>>(yb, wqkv_t + (size_t)l * 2304 * 768, bqkv + (size_t)l * 2304, nullptr, qkvb, MR, 2304, 768);
        attn2_k<<<dim3(H_, B_), blk, 0, stream>>>(qkvb, yb);
        mm_t<2, 128, 4><<<dim3(6, 100), blk, 0, stream>>>(yb, wp_t + oDD, pb + oD, h, h, MR, 768, 768);
        ln4_k<true><<<dim3(M_ / 4), blk, 0, stream>>>(h, 768, yb, 768, ln2_s + oD, ln2_b + oD, M_);
        mm_t<1, 256, 8><<<dim3(12, 100), blk512, 0, stream>>>(yb, w1_t + oDF, fc1_b + oF, nullptr, ub, MR, FF_, 768);
        mm_t<2, 128, 4><<<dim3(6, 100), blk, 0, stream>>>(ub, w2_t + oDF, fc2_b + oD, h, h, MR, 768, FF_);
    }

    // ---- final LN on CLS rows ----
    ln4_k<false><<<dim3(B_ / 4), blk, 0, stream>>>(h, (size_t)S_ * D_, out, 768, lnf_s, lnf_b, B_);
}

// Round 16
// 4081.631 us; speedup vs baseline: 1.0259x; 1.0001x over previous
//
#include <hip/hip_runtime.h>
#include <math.h>

// ---- problem constants ----
constexpr int B_   = 64;
constexpr int S_   = 197;
constexpr int D_   = 768;
constexpr int H_   = 12;
constexpr int FF_  = 3072;
constexpr int DEPTH_ = 12;
constexpr int NP_  = 196;
constexpr int M_   = B_ * S_;    // 12608
constexpr int MP_  = B_ * NP_;   // 12544
constexpr int MR   = 12800;      // 100*128 padded rows

typedef __attribute__((ext_vector_type(8))) short  bf16x8;
typedef __attribute__((ext_vector_type(4))) short  short4_t;
typedef __attribute__((ext_vector_type(4))) float  f32x4;
typedef unsigned short ushort_t;

__device__ __forceinline__ ushort_t f2bf(float x) {
    unsigned u = __builtin_bit_cast(unsigned, x);
    unsigned r = u + 0x7FFFu + ((u >> 16) & 1u);
    return (ushort_t)(r >> 16);
}

// fast GELU (tanh form): max abs dev from exact erf-GELU ~3e-3, fine for bf16
__device__ __forceinline__ float gelu_f(float v) {
    float y = 0.7978845608f * v + 0.0356774081f * (v * v * v);
    float e = __builtin_amdgcn_exp2f(2.88539008178f * y);    // e^(2y)
    float t = 1.0f - 2.0f * __builtin_amdgcn_rcpf(1.0f + e); // tanh(y)
    return 0.5f * v * (1.0f + t);
}

#define GLOAD_LDS16(g, l)                                                      \
    __builtin_amdgcn_global_load_lds(                                          \
        (const __attribute__((address_space(1))) void*)(g),                    \
        (__attribute__((address_space(3))) void*)(l), 16, 0, 0)

// ===== 128xBN MFMA GEMM, fine-phase + 3-slot ring (R10/R13-verified best) =====
// C[M,N] = epi(A[M,K] @ Bt[N,K]^T + bias)   A,Bt bf16; acc f32.
// EPI: 0 = bf16 out, 1 = bf16 out + GELU, 2 = f32 out + residual, 3 = f32 out.
// BM=128. (BN=256, 8 waves): 72KB LDS. (BN=128, 4 waves): 48KB -> 3 blocks/CU.
// LDS slice layout row-major: byte = row*64 + (chunk ^ ((row>>1)&3))*16.
// Conflict-free both sides (R10: SQ_LDS_BANK_CONFLICT == 0, FETCH unchanged).
// Per phase: 8 ds_read_b128 + stage slice s+2 -> barrier -> lgkmcnt(0) ->
// setprio(1) 16 MFMA -> counted vmcnt(LV) -> barrier. Never drain-0 mid-loop.
// NOTE (R12): wide-N ops (QKV, fc1) stay BN=256/8-wave (A-panel L2 reuse).
// NOTE (R14): single-barrier variant was neutral (within noise); keeping two.

template<int EPI, int BN, int NWAVE>
__global__ __launch_bounds__(NWAVE * 64, (NWAVE == 8) ? 4 : 3)
void mm_t(const ushort_t* __restrict__ A, const ushort_t* __restrict__ Bt,
          const float* __restrict__ bias, const float* __restrict__ res,
          void* __restrict__ Cout, int M, int N, int K) {
    constexpr int THREADS = NWAVE * 64;
    constexpr int SLICE   = (128 + BN) * 64;      // bytes per slice (A 8KB | B BN*64)
    constexpr int PASSB   = THREADS * 16;         // bytes staged per pass
    constexpr int PA      = 8192 / PASSB;         // A passes per slice
    constexpr int PB      = (BN * 64) / PASSB;    // B passes per slice
    constexpr int LV      = PA + PB;              // gload_lds per thread per slice
    __shared__ __align__(16) char lds[3 * SLICE];

    const int tid  = threadIdx.x;
    const int wid  = tid >> 6;
    const int lane = tid & 63;

    // bijective XCD-chunked swizzle (m204)
    const int nwg  = gridDim.x * gridDim.y;
    const int orig = blockIdx.y * gridDim.x + blockIdx.x;
    const int xcd  = orig & 7, slot = orig >> 3;
    const int q8   = nwg >> 3, r8 = nwg & 7;
    const int logical = (xcd < r8 ? xcd * (q8 + 1) : r8 * (q8 + 1) + (xcd - r8) * q8) + slot;
    const int m0 = (logical / gridDim.x) * 128;
    const int n0 = (logical % gridDim.x) * BN;

    const int wr  = (NWAVE == 8) ? (wid >> 2) : (wid >> 1);   // row half
    const int wcn = (NWAVE == 8) ? (wid & 3)  : (wid & 1);    // col group (64 cols)
    const int l15 = lane & 15, kq = lane >> 4;

    // read-side fragment byte offsets within a slice (R10 swizzle)
    const int chb   = ((kq ^ ((l15 >> 1) & 3)) & 3) * 16;
    const int abase = wr * 4096 + l15 * 64 + chb;            // + m*1024
    const int bbase = 8192 + wcn * 4096 + l15 * 64 + chb;    // + n*1024

    // stage-side: thread t covers row srow (+p*THREADS/4), chunk sc (pre-swizzled)
    const int srow = tid >> 2;
    const int sc   = (tid & 3) ^ ((tid >> 3) & 3);
    size_t gA[PA], gB[PB];
    #pragma unroll
    for (int p = 0; p < PA; ++p) gA[p] = (size_t)(m0 + srow + p * (THREADS / 4)) * K + sc * 8;
    #pragma unroll
    for (int p = 0; p < PB; ++p) gB[p] = (size_t)(n0 + srow + p * (THREADS / 4)) * K + sc * 8;

    f32x4 acc[4][4];
    #pragma unroll
    for (int m = 0; m < 4; ++m)
        #pragma unroll
        for (int n = 0; n < 4; ++n)
            acc[m][n] = (f32x4){0.f, 0.f, 0.f, 0.f};

#define MMT_STAGE(ss)                                                          \
    { char* d_ = lds + ((ss) % 3) * SLICE + wid * 1024;                        \
      const size_t ko_ = (size_t)(ss) * 32;                                    \
      _Pragma("unroll")                                                        \
      for (int p = 0; p < PA; ++p) GLOAD_LDS16(A + gA[p] + ko_, d_ + p * PASSB); \
      _Pragma("unroll")                                                        \
      for (int p = 0; p < PB; ++p) GLOAD_LDS16(Bt + gB[p] + ko_, d_ + 8192 + p * PASSB); }

#define MMT_VMW()                                                              \
    { if constexpr (LV == 3) { asm volatile("s_waitcnt vmcnt(3)" ::: "memory"); } \
      else                   { asm volatile("s_waitcnt vmcnt(4)" ::: "memory"); } }

#define MMT_PHASE(s_, DOSTAGE, FINAL)                                          \
  { const char* sb_ = lds + ((s_) % 3) * SLICE;                                \
    bf16x8 av[4], bv[4];                                                       \
    _Pragma("unroll")                                                          \
    for (int m = 0; m < 4; ++m) av[m] = *(const bf16x8*)(sb_ + abase + m * 1024); \
    _Pragma("unroll")                                                          \
    for (int n = 0; n < 4; ++n) bv[n] = *(const bf16x8*)(sb_ + bbase + n * 1024); \
    if (DOSTAGE) MMT_STAGE((s_) + 2);                                          \
    __builtin_amdgcn_sched_barrier(0);                                         \
    __builtin_amdgcn_s_barrier();                                              \
    asm volatile("s_waitcnt lgkmcnt(0)" ::: "memory");                         \
    __builtin_amdgcn_sched_barrier(0);                                         \
    __builtin_amdgcn_s_setprio(1);                                             \
    _Pragma("unroll")                                                          \
    for (int m = 0; m < 4; ++m)                                                \
      _Pragma("unroll")                                                        \
      for (int n = 0; n < 4; ++n)                                              \
        acc[m][n] = __builtin_amdgcn_mfma_f32_16x16x32_bf16(av[m], bv[n], acc[m][n], 0, 0, 0); \
    __builtin_amdgcn_s_setprio(0);                                             \
    if (FINAL) { asm volatile("s_waitcnt vmcnt(0)" ::: "memory"); }            \
    else       { MMT_VMW(); }                                                  \
    __builtin_amdgcn_sched_barrier(0);                                         \
    __builtin_amdgcn_s_barrier(); }

    // prologue: slices 0,1 in flight; complete slice 0
    MMT_STAGE(0); MMT_STAGE(1);
    MMT_VMW();
    __builtin_amdgcn_s_barrier();

    const int NS = K >> 5;
    for (int s = 0; s < NS - 2; ++s) {
        MMT_PHASE(s, true, false);
    }
    MMT_PHASE(NS - 2, false, true);
    MMT_PHASE(NS - 1, false, true);

#undef MMT_STAGE
#undef MMT_VMW
#undef MMT_PHASE

    // epilogue: rows m0+wr*64+m*16+kq*4+j, cols n0+wcn*64+n*16+l15
    #pragma unroll
    for (int n = 0; n < 4; ++n) {
        const int col = n0 + wcn * 64 + n * 16 + l15;
        const float bcol = bias[col];
        #pragma unroll
        for (int m = 0; m < 4; ++m) {
            #pragma unroll
            for (int j = 0; j < 4; ++j) {
                const int row = m0 + wr * 64 + m * 16 + kq * 4 + j;
                float v = acc[m][n][j] + bcol;
                if (EPI == 1) v = gelu_f(v);
                if (EPI == 2) v += res[(size_t)row * N + col];
                if (EPI <= 1) ((ushort_t*)Cout)[(size_t)row * N + col] = f2bf(v);
                else          ((float*)Cout)[(size_t)row * N + col] = v;
            }
        }
    }
}

// ====================== MFMA attention ======================
constexpr int SKV = 224;     // padded KV length (7 k-tiles of 32)
constexpr int VLD = 232;     // padded Vt row length (elements)

// K staged via global_load_lds with per-lane pre-swizzled SOURCE (rule #21):
// linear dest (wave-uniform base + lane*16); lane l of wave w covers row
// j = pass*32 + w*8 + (l>>3), LDS slot (l&7); source dh-chunk (l&7)^(j&7) so
// slot s holds chunk s^(j&7) — matching the existing swizzled read.
// Out-of-range rows (j>=197) load adjacent/pad qkv rows: always finite
// (GEMM outputs), and masked by the j<S_ -> p=0 softmax logic (0*finite=0).
__global__ __launch_bounds__(256)
void attn2_k(const ushort_t* __restrict__ qkv, ushort_t* __restrict__ o) {
    __shared__ __align__(16) ushort_t Ks[SKV * 64];   // [j][dh], XOR-swizzled
    __shared__ __align__(16) ushort_t Vt[64 * VLD];   // [dh][j], XOR-swizzled (R12)
    __shared__ __align__(16) ushort_t Pw[4 * 512];    // per-wave 16x32, swizzled
    const int h = blockIdx.x, b = blockIdx.y;
    const int tid = threadIdx.x, wid = tid >> 6, lane = tid & 63;
    const size_t baseq = (size_t)(b * S_) * 2304 + h * 64;
    char* const vtb = (char*)Vt;

    {
        const int jr  = tid >> 3;          // 0..31 (V path)
        const int dh0 = (tid & 7) * 8;
        const int jk  = wid * 8 + (lane >> 3);   // K path: row within pass
        #pragma unroll
        for (int pass = 0; pass < 7; ++pass) {
            // K: direct-to-LDS DMA, pre-swizzled source chunk
            const int j  = pass * 32 + jk;
            const int cs = (lane & 7) ^ (j & 7);
            GLOAD_LDS16(qkv + baseq + (size_t)j * 2304 + 768 + cs * 8,
                        (char*)Ks + (pass * 32 + wid * 8) * 128);
            // V: reg-staged transpose (unconditional; finite garbage masked)
            const int j2 = pass * 32 + jr;
            bf16x8 vv = *(const bf16x8*)&qkv[baseq + (size_t)j2 * 2304 + 1536 + dh0];
            #pragma unroll
            for (int i = 0; i < 8; ++i)
                *(ushort_t*)(vtb + ((((dh0 + i) * VLD + j2) * 2) ^ ((tid & 7) << 4))) = (ushort_t)vv[i];
        }
    }
    __syncthreads();   // full vmcnt/lgkm drain covers the K DMA + V writes

    char* const pwb = (char*)Pw + wid * 1024;

    for (int it = 0; it < 4; ++it) {
        int sq = it * 64 + wid * 16 + (lane & 15);
        const int sqc = (sq < S_) ? sq : (S_ - 1);
        bf16x8 qf[2];
        #pragma unroll
        for (int kk = 0; kk < 2; ++kk)
            qf[kk] = *(const bf16x8*)&qkv[baseq + (size_t)sqc * 2304 + kk * 32 + (lane >> 4) * 8];

        f32x4 sa[14];
        #pragma unroll
        for (int nf = 0; nf < 14; ++nf) sa[nf] = (f32x4){0.f, 0.f, 0.f, 0.f};
        #pragma unroll
        for (int kk = 0; kk < 2; ++kk) {
            #pragma unroll
            for (int nf = 0; nf < 14; ++nf) {
                const int j = nf * 16 + (lane & 15);
                const int off = (j * 128 + kk * 64 + (lane >> 4) * 16) ^ ((j & 7) << 4);
                bf16x8 kf = *(const bf16x8*)((const char*)Ks + off);
                sa[nf] = __builtin_amdgcn_mfma_f32_16x16x32_bf16(qf[kk], kf, sa[nf], 0, 0, 0);
            }
        }

        const int jcol = lane & 15;
        float mx[4] = {-1e30f, -1e30f, -1e30f, -1e30f};
        #pragma unroll
        for (int nf = 0; nf < 14; ++nf)
            #pragma unroll
            for (int r = 0; r < 4; ++r) mx[r] = fmaxf(mx[r], sa[nf][r]);
        float ls[4];
        #pragma unroll
        for (int r = 0; r < 4; ++r) {
            float m = mx[r] * 0.125f;
            m = fmaxf(m, __shfl_xor(m, 1, 64));
            m = fmaxf(m, __shfl_xor(m, 2, 64));
            m = fmaxf(m, __shfl_xor(m, 4, 64));
            m = fmaxf(m, __shfl_xor(m, 8, 64));
            float s = 0.f;
            #pragma unroll
            for (int nf = 0; nf < 14; ++nf) {
                const int j = nf * 16 + jcol;
                float p = (j < S_) ? exp2f((sa[nf][r] * 0.125f - m) * 1.44269504088896f) : 0.f;
                sa[nf][r] = p;
                s += p;
            }
            s += __shfl_xor(s, 1, 64);
            s += __shfl_xor(s, 2, 64);
            s += __shfl_xor(s, 4, 64);
            s += __shfl_xor(s, 8, 64);
            ls[r] = s;
        }

        f32x4 oa[4];
        #pragma unroll
        for (int nf = 0; nf < 4; ++nf) oa[nf] = (f32x4){0.f, 0.f, 0.f, 0.f};
        #pragma unroll
        for (int kt = 0; kt < 7; ++kt) {
            #pragma unroll
            for (int half = 0; half < 2; ++half) {
                #pragma unroll
                for (int r = 0; r < 4; ++r) {
                    const int qr = (lane >> 4) * 4 + r;
                    const int jl = half * 16 + jcol;
                    const int off = (qr * 64 + jl * 2) ^ (((qr >> 1) & 3) << 4);
                    *(ushort_t*)(pwb + off) = f2bf(sa[kt * 2 + half][r]);
                }
            }
            const int arow = lane & 15;
            const int aoff2 = (arow * 64 + (lane >> 4) * 16) ^ (((arow >> 1) & 3) << 4);
            bf16x8 pa = *(const bf16x8*)(pwb + aoff2);
            #pragma unroll
            for (int nf = 0; nf < 4; ++nf) {
                const int dh = nf * 16 + (lane & 15);
                const int voff = ((dh * VLD + kt * 32 + (lane >> 4) * 8) * 2) ^ ((((nf * 2) + ((lane & 15) >> 3)) & 7) << 4);
                bf16x8 vb = *(const bf16x8*)(vtb + voff);
                oa[nf] = __builtin_amdgcn_mfma_f32_16x16x32_bf16(pa, vb, oa[nf], 0, 0, 0);
            }
        }

        #pragma unroll
        for (int r = 0; r < 4; ++r) {
            const int so = it * 64 + wid * 16 + (lane >> 4) * 4 + r;
            if (so < S_) {
                const float inv = 1.0f / ls[r];
                #pragma unroll
                for (int nf = 0; nf < 4; ++nf)
                    o[(size_t)(b * S_ + so) * 768 + h * 64 + nf * 16 + (lane & 15)] = f2bf(oa[nf][r] * inv);
            }
        }
    }
}

// ====================== small kernels ======================
__global__ __launch_bounds__(256)
void tcast_k(const float* __restrict__ in, ushort_t* __restrict__ out,
             int R, int C, size_t in_ls, size_t out_ls) {
    __shared__ float t[32][33];
    const float* ip = in + (size_t)blockIdx.z * in_ls;
    ushort_t* op = out + (size_t)blockIdx.z * out_ls;
    const int c0 = blockIdx.x * 32, r0 = blockIdx.y * 32;
    const int tx = threadIdx.x & 31, ty = threadIdx.x >> 5;
    #pragma unroll
    for (int i = 0; i < 4; ++i)
        t[ty + i * 8][tx] = ip[(size_t)(r0 + ty + i * 8) * C + c0 + tx];
    __syncthreads();
    #pragma unroll
    for (int i = 0; i < 4; ++i)
        op[(size_t)(c0 + ty + i * 8) * R + r0 + tx] = f2bf(t[tx][ty + i * 8]);
}

__global__ void cast_k(const float* __restrict__ in, ushort_t* __restrict__ out, int n) {
    int i = blockIdx.x * 256 + threadIdx.x;
    if (i < n) out[i] = f2bf(in[i]);
}

__global__ void biascat_k(const float* __restrict__ qb, const float* __restrict__ kb,
                          const float* __restrict__ vb, float* __restrict__ out) {
    int i = blockIdx.x * 256 + threadIdx.x;       // l*2304 + n
    if (i >= DEPTH_ * 2304) return;
    int l = i / 2304, n = i % 2304;
    float v = (n < 768) ? qb[l * 768 + n] : (n < 1536) ? kb[l * 768 + n - 768] : vb[l * 768 + n - 1536];
    out[i] = v;
}

__global__ void im2col_k(const float* __restrict__ x, ushort_t* __restrict__ pm) {
    size_t idx = (size_t)blockIdx.x * 256 + threadIdx.x;
    if (idx >= (size_t)MP_ * 768) return;
    int col = (int)(idx % 768);
    int row = (int)(idx / 768);
    int b = row / NP_, p = row % NP_;
    int c = col >> 8, rem = col & 255, ky = rem >> 4, kx = rem & 15;
    int py = p / 14, px = p % 14;
    pm[idx] = f2bf(x[(((size_t)b * 3 + c) * 224 + (py * 16 + ky)) * 224 + (px * 16 + kx)]);
}

__global__ void assemble_k(const float* __restrict__ pe, const float* __restrict__ cls,
                           const float* __restrict__ pos, float* __restrict__ h) {
    size_t idx = (size_t)blockIdx.x * 256 + threadIdx.x;
    if (idx >= (size_t)M_ * D_) return;
    int d = (int)(idx % D_);
    int row = (int)(idx / D_);
    int b = row / S_, s = row % S_;
    float v;
    if (s == 0) v = cls[d] + pos[d];
    else        v = pe[((size_t)b * NP_ + (s - 1)) * D_ + d] + pos[(size_t)s * D_ + d];
    h[idx] = v;
}

// ======= vectorized LayerNorm: 4 rows/block, one wave per row (R15) =======
template<bool BF16OUT>
__global__ __launch_bounds__(256)
void ln4_k(const float* __restrict__ x, size_t xstride,
           void* __restrict__ y, size_t ystride,
           const float* __restrict__ s, const float* __restrict__ b, int nrows) {
    const int wid = threadIdx.x >> 6, lane = threadIdx.x & 63;
    const int row = blockIdx.x * 4 + wid;
    if (row >= nrows) return;
    const float* xr = x + (size_t)row * xstride;

    f32x4 v[3];
    float sum = 0.f;
    #pragma unroll
    for (int t = 0; t < 3; ++t) {
        v[t] = *(const f32x4*)&xr[lane * 4 + t * 256];
        sum += (v[t][0] + v[t][1]) + (v[t][2] + v[t][3]);
    }
    #pragma unroll
    for (int off = 32; off > 0; off >>= 1) sum += __shfl_xor(sum, off, 64);
    const float mu = sum * (1.0f / 768.0f);

    float vs = 0.f;
    #pragma unroll
    for (int t = 0; t < 3; ++t)
        #pragma unroll
        for (int e = 0; e < 4; ++e) { float d = v[t][e] - mu; vs += d * d; }
    #pragma unroll
    for (int off = 32; off > 0; off >>= 1) vs += __shfl_xor(vs, off, 64);
    const float rstd = rsqrtf(vs * (1.0f / 768.0f) + 1e-6f);

    #pragma unroll
    for (int t = 0; t < 3; ++t) {
        const int c = lane * 4 + t * 256;
        const f32x4 sv = *(const f32x4*)&s[c];
        const f32x4 bv = *(const f32x4*)&b[c];
        if (BF16OUT) {
            short4_t o4;
            #pragma unroll
            for (int e = 0; e < 4; ++e)
                o4[e] = (short)f2bf((v[t][e] - mu) * rstd * sv[e] + bv[e]);
            *(short4_t*)((ushort_t*)y + (size_t)row * ystride + c) = o4;
        } else {
            f32x4 o;
            #pragma unroll
            for (int e = 0; e < 4; ++e)
                o[e] = (v[t][e] - mu) * rstd * sv[e] + bv[e];
            *(f32x4*)((float*)y + (size_t)row * ystride + c) = o;
        }
    }
}

// ====================== launch ======================
extern "C" void kernel_launch(void* const* d_in, const int* in_sizes, int n_in,
                              void* d_out, int out_size, void* d_ws, size_t ws_size,
                              hipStream_t stream) {
    const float* x       = (const float*)d_in[0];
    const float* patch_w = (const float*)d_in[1];
    const float* patch_b = (const float*)d_in[2];
    const float* cls_tok = (const float*)d_in[3];
    const float* pos_emb = (const float*)d_in[4];
    const float* ln1_s   = (const float*)d_in[5];
    const float* ln1_b   = (const float*)d_in[6];
    const float* qw      = (const float*)d_in[7];
    const float* qb      = (const float*)d_in[8];
    const float* kw      = (const float*)d_in[9];
    const float* kb      = (const float*)d_in[10];
    const float* vw      = (const float*)d_in[11];
    const float* vb      = (const float*)d_in[12];
    const float* pw      = (const float*)d_in[13];
    const float* pb      = (const float*)d_in[14];
    const float* ln2_s   = (const float*)d_in[15];
    const float* ln2_b   = (const float*)d_in[16];
    const float* fc1_w   = (const float*)d_in[17];
    const float* fc1_b   = (const float*)d_in[18];
    const float* fc2_w   = (const float*)d_in[19];
    const float* fc2_b   = (const float*)d_in[20];
    const float* lnf_s   = (const float*)d_in[21];
    const float* lnf_b   = (const float*)d_in[22];
    float* out = (float*)d_out;

    // ---- workspace layout (bytes) ----
    char* ws = (char*)d_ws;
    float*    h      = (float*)ws;                                   // MR*768 f32
    ushort_t* yb     = (ushort_t*)(ws + 39321600);                   // MR*768 bf16
    char*     Ubase  = ws + 58982400;                                 // shared region (MR*3072 bf16 max)
    ushort_t* qkvb   = (ushort_t*)Ubase;                              // MR*2304 bf16
    ushort_t* ub     = (ushort_t*)Ubase;                              // MR*3072 bf16
    float*    peb    = (float*)Ubase;                                 // MR*768 f32 (prologue)
    ushort_t* wqkv_t = (ushort_t*)(ws + 137625600);                   // 12*2304*768
    ushort_t* wp_t   = (ushort_t*)(ws + 180092928);                   // 12*768*768
    ushort_t* w1_t   = (ushort_t*)(ws + 194248704);                   // 12*3072*768
    ushort_t* w2_t   = (ushort_t*)(ws + 250871808);                   // 12*768*3072
    ushort_t* pwt    = (ushort_t*)(ws + 307494912);                   // 768*768
    float*    bqkv   = (float*)(ws + 308674560);                      // 12*2304 f32

    const dim3 blk(256);
    const dim3 blk512(512);

    // ---- weight prep ----
    tcast_k<<<dim3(768 / 32, 768 / 32, 12), blk, 0, stream>>>(qw, wqkv_t,            768, 768, (size_t)768 * 768, (size_t)2304 * 768);
    tcast_k<<<dim3(768 / 32, 768 / 32, 12), blk, 0, stream>>>(kw, wqkv_t + 768 * 768, 768, 768, (size_t)768 * 768, (size_t)2304 * 768);
    tcast_k<<<dim3(768 / 32, 768 / 32, 12), blk, 0, stream>>>(vw, wqkv_t + 1536 * 768, 768, 768, (size_t)768 * 768, (size_t)2304 * 768);
    tcast_k<<<dim3(768 / 32, 768 / 32, 12), blk, 0, stream>>>(pw, wp_t, 768, 768, (size_t)768 * 768, (size_t)768 * 768);
    tcast_k<<<dim3(3072 / 32, 768 / 32, 12), blk, 0, stream>>>(fc1_w, w1_t, 768, 3072, (size_t)768 * 3072, (size_t)3072 * 768);
    tcast_k<<<dim3(768 / 32, 3072 / 32, 12), blk, 0, stream>>>(fc2_w, w2_t, 3072, 768, (size_t)3072 * 768, (size_t)768 * 3072);
    cast_k<<<dim3((768 * 768 + 255) / 256), blk, 0, stream>>>(patch_w, pwt, 768 * 768);
    biascat_k<<<dim3((DEPTH_ * 2304 + 255) / 256), blk, 0, stream>>>(qb, kb, vb, bqkv);

    // ---- patch embed ----
    im2col_k<<<dim3(((size_t)MP_ * 768 + 255) / 256), blk, 0, stream>>>(x, yb);
    mm_t<3, 128, 4><<<dim3(6, 100), blk, 0, stream>>>(yb, pwt, patch_b, nullptr, peb, MR, 768, 768);
    assemble_k<<<dim3(((size_t)M_ * D_ + 255) / 256), blk, 0, stream>>>(peb, cls_tok, pos_emb, h);

    // ---- transformer blocks ----
    for (int l = 0; l < DEPTH_; ++l) {
        const size_t oDD = (size_t)l * 768 * 768;
        const size_t oD  = (size_t)l * 768;
        const size_t oDF = (size_t)l * 768 * FF_;
        const size_t oF  = (size_t)l * FF_;

        ln4_k<true><<<dim3(M_ / 4), blk, 0, stream>>>(h, 768, yb, 768, ln1_s + oD, ln1_b + oD, M_);
        mm_t<0, 256, 8><<<dim3(9, 100), blk512, 0, stream>>>(yb, wqkv_t + (size_t)l * 2304 * 768, bqkv + (size_t)l * 2304, nullptr, qkvb, MR, 2304, 768);
        attn2_k<<<dim3(H_, B_), blk, 0, stream>>>(qkvb, yb);
        mm_t<2, 128, 4><<<dim3(6, 100), blk, 0, stream>>>(yb, wp_t + oDD, pb + oD, h, h, MR, 768, 768);
        ln4_k<true><<<dim3(M_ / 4), blk, 0, stream>>>(h, 768, yb, 768, ln2_s + oD, ln2_b + oD, M_);
        mm_t<1, 256, 8><<<dim3(12, 100), blk512, 0, stream>>>(yb, w1_t + oDF, fc1_b + oF, nullptr, ub, MR, FF_, 768);
        mm_t<2, 128, 4><<<dim3(6, 100), blk, 0, stream>>>(ub, w2_t + oDF, fc2_b + oD, h, h, MR, 768, FF_);
    }

    // ---- final LN on CLS rows ----
    ln4_k<false><<<dim3(B_ / 4), blk, 0, stream>>>(h, (size_t)S_ * D_, out, 768, lnf_s, lnf_b, B_);
}

// Round 17
// 4058.434 us; speedup vs baseline: 1.0318x; 1.0057x over previous
//
#include <hip/hip_runtime.h>
#include <math.h>

// ---- problem constants ----
constexpr int B_   = 64;
constexpr int S_   = 197;
constexpr int D_   = 768;
constexpr int H_   = 12;
constexpr int FF_  = 3072;
constexpr int DEPTH_ = 12;
constexpr int NP_  = 196;
constexpr int M_   = B_ * S_;    // 12608
constexpr int MP_  = B_ * NP_;   // 12544
constexpr int MR   = 12800;      // 100*128 padded rows

typedef __attribute__((ext_vector_type(8))) short  bf16x8;
typedef __attribute__((ext_vector_type(4))) short  short4_t;
typedef __attribute__((ext_vector_type(4))) float  f32x4;
typedef unsigned short ushort_t;

__device__ __forceinline__ ushort_t f2bf(float x) {
    unsigned u = __builtin_bit_cast(unsigned, x);
    unsigned r = u + 0x7FFFu + ((u >> 16) & 1u);
    return (ushort_t)(r >> 16);
}

// fast GELU (tanh form): max abs dev from exact erf-GELU ~3e-3, fine for bf16
__device__ __forceinline__ float gelu_f(float v) {
    float y = 0.7978845608f * v + 0.0356774081f * (v * v * v);
    float e = __builtin_amdgcn_exp2f(2.88539008178f * y);    // e^(2y)
    float t = 1.0f - 2.0f * __builtin_amdgcn_rcpf(1.0f + e); // tanh(y)
    return 0.5f * v * (1.0f + t);
}

#define GLOAD_LDS16(g, l)                                                      \
    __builtin_amdgcn_global_load_lds(                                          \
        (const __attribute__((address_space(1))) void*)(g),                    \
        (__attribute__((address_space(3))) void*)(l), 16, 0, 0)

// ===== 128xBN MFMA GEMM, fine-phase + 3-slot ring, compiler-scheduled (R17) =====
// C[M,N] = epi(A[M,K] @ Bt[N,K]^T + bias)   A,Bt bf16; acc f32.
// EPI: 0 = bf16 out, 1 = bf16 out + GELU, 2 = f32 out + residual, 3 = f32 out.
// BM=128. (BN=256, 8 waves): 72KB LDS. (BN=128, 4 waves): 48KB -> 3 blocks/CU.
// LDS slice layout row-major: byte = row*64 + (chunk ^ ((row>>1)&3))*16.
// Conflict-free both sides (R10: SQ_LDS_BANK_CONFLICT == 0).
// R17 change (m141 lesson): NO explicit lgkmcnt(0)/sched_barrier — the frag
// reads are compiler-visible loads; the compiler emits fine-grained lgkmcnt
// interleaving reads with MFMA. Raw s_barriers kept (syncthreads would drain
// vmcnt to 0, killing the counted pipeline); counted vmcnt(LV) kept.
// Safety: frag reads (slot s%3) complete before end barrier via MFMA data
// dependence; stages target slot (s-1)%3 — disjoint.
// NOTE (R12): wide-N ops (QKV, fc1) stay BN=256/8-wave (A-panel L2 reuse).

template<int EPI, int BN, int NWAVE>
__global__ __launch_bounds__(NWAVE * 64, (NWAVE == 8) ? 4 : 3)
void mm_t(const ushort_t* __restrict__ A, const ushort_t* __restrict__ Bt,
          const float* __restrict__ bias, const float* __restrict__ res,
          void* __restrict__ Cout, int M, int N, int K) {
    constexpr int THREADS = NWAVE * 64;
    constexpr int SLICE   = (128 + BN) * 64;      // bytes per slice (A 8KB | B BN*64)
    constexpr int PASSB   = THREADS * 16;         // bytes staged per pass
    constexpr int PA      = 8192 / PASSB;         // A passes per slice
    constexpr int PB      = (BN * 64) / PASSB;    // B passes per slice
    constexpr int LV      = PA + PB;              // gload_lds per thread per slice
    __shared__ __align__(16) char lds[3 * SLICE];

    const int tid  = threadIdx.x;
    const int wid  = tid >> 6;
    const int lane = tid & 63;

    // bijective XCD-chunked swizzle (m204)
    const int nwg  = gridDim.x * gridDim.y;
    const int orig = blockIdx.y * gridDim.x + blockIdx.x;
    const int xcd  = orig & 7, slot = orig >> 3;
    const int q8   = nwg >> 3, r8 = nwg & 7;
    const int logical = (xcd < r8 ? xcd * (q8 + 1) : r8 * (q8 + 1) + (xcd - r8) * q8) + slot;
    const int m0 = (logical / gridDim.x) * 128;
    const int n0 = (logical % gridDim.x) * BN;

    const int wr  = (NWAVE == 8) ? (wid >> 2) : (wid >> 1);   // row half
    const int wcn = (NWAVE == 8) ? (wid & 3)  : (wid & 1);    // col group (64 cols)
    const int l15 = lane & 15, kq = lane >> 4;

    // read-side fragment byte offsets within a slice (R10 swizzle)
    const int chb   = ((kq ^ ((l15 >> 1) & 3)) & 3) * 16;
    const int abase = wr * 4096 + l15 * 64 + chb;            // + m*1024
    const int bbase = 8192 + wcn * 4096 + l15 * 64 + chb;    // + n*1024

    // stage-side: thread t covers row srow (+p*THREADS/4), chunk sc (pre-swizzled)
    const int srow = tid >> 2;
    const int sc   = (tid & 3) ^ ((tid >> 3) & 3);
    size_t gA[PA], gB[PB];
    #pragma unroll
    for (int p = 0; p < PA; ++p) gA[p] = (size_t)(m0 + srow + p * (THREADS / 4)) * K + sc * 8;
    #pragma unroll
    for (int p = 0; p < PB; ++p) gB[p] = (size_t)(n0 + srow + p * (THREADS / 4)) * K + sc * 8;

    f32x4 acc[4][4];
    #pragma unroll
    for (int m = 0; m < 4; ++m)
        #pragma unroll
        for (int n = 0; n < 4; ++n)
            acc[m][n] = (f32x4){0.f, 0.f, 0.f, 0.f};

#define MMT_STAGE(ss)                                                          \
    { char* d_ = lds + ((ss) % 3) * SLICE + wid * 1024;                        \
      const size_t ko_ = (size_t)(ss) * 32;                                    \
      _Pragma("unroll")                                                        \
      for (int p = 0; p < PA; ++p) GLOAD_LDS16(A + gA[p] + ko_, d_ + p * PASSB); \
      _Pragma("unroll")                                                        \
      for (int p = 0; p < PB; ++p) GLOAD_LDS16(Bt + gB[p] + ko_, d_ + 8192 + p * PASSB); }

#define MMT_VMW()                                                              \
    { if constexpr (LV == 3) { asm volatile("s_waitcnt vmcnt(3)" ::: "memory"); } \
      else                   { asm volatile("s_waitcnt vmcnt(4)" ::: "memory"); } }

#define MMT_PHASE(s_, DOSTAGE, FINAL)                                          \
  { const char* sb_ = lds + ((s_) % 3) * SLICE;                                \
    bf16x8 av[4], bv[4];                                                       \
    _Pragma("unroll")                                                          \
    for (int m = 0; m < 4; ++m) av[m] = *(const bf16x8*)(sb_ + abase + m * 1024); \
    _Pragma("unroll")                                                          \
    for (int n = 0; n < 4; ++n) bv[n] = *(const bf16x8*)(sb_ + bbase + n * 1024); \
    if (DOSTAGE) MMT_STAGE((s_) + 2);                                          \
    __builtin_amdgcn_s_barrier();                                              \
    __builtin_amdgcn_s_setprio(1);                                             \
    _Pragma("unroll")                                                          \
    for (int m = 0; m < 4; ++m)                                                \
      _Pragma("unroll")                                                        \
      for (int n = 0; n < 4; ++n)                                              \
        acc[m][n] = __builtin_amdgcn_mfma_f32_16x16x32_bf16(av[m], bv[n], acc[m][n], 0, 0, 0); \
    __builtin_amdgcn_s_setprio(0);                                             \
    if (FINAL) { asm volatile("s_waitcnt vmcnt(0)" ::: "memory"); }            \
    else       { MMT_VMW(); }                                                  \
    __builtin_amdgcn_s_barrier(); }

    // prologue: slices 0,1 in flight; complete slice 0
    MMT_STAGE(0); MMT_STAGE(1);
    MMT_VMW();
    __builtin_amdgcn_s_barrier();

    const int NS = K >> 5;
    for (int s = 0; s < NS - 2; ++s) {
        MMT_PHASE(s, true, false);
    }
    MMT_PHASE(NS - 2, false, true);
    MMT_PHASE(NS - 1, false, true);

#undef MMT_STAGE
#undef MMT_VMW
#undef MMT_PHASE

    // epilogue: rows m0+wr*64+m*16+kq*4+j, cols n0+wcn*64+n*16+l15
    #pragma unroll
    for (int n = 0; n < 4; ++n) {
        const int col = n0 + wcn * 64 + n * 16 + l15;
        const float bcol = bias[col];
        #pragma unroll
        for (int m = 0; m < 4; ++m) {
            #pragma unroll
            for (int j = 0; j < 4; ++j) {
                const int row = m0 + wr * 64 + m * 16 + kq * 4 + j;
                float v = acc[m][n][j] + bcol;
                if (EPI == 1) v = gelu_f(v);
                if (EPI == 2) v += res[(size_t)row * N + col];
                if (EPI <= 1) ((ushort_t*)Cout)[(size_t)row * N + col] = f2bf(v);
                else          ((float*)Cout)[(size_t)row * N + col] = v;
            }
        }
    }
}

// ====================== MFMA attention ======================
constexpr int SKV = 224;     // padded KV length (7 k-tiles of 32)
constexpr int VLD = 232;     // padded Vt row length (elements)

__global__ __launch_bounds__(256)
void attn2_k(const ushort_t* __restrict__ qkv, ushort_t* __restrict__ o) {
    __shared__ __align__(16) ushort_t Ks[SKV * 64];   // [j][dh], XOR-swizzled
    __shared__ __align__(16) ushort_t Vt[64 * VLD];   // [dh][j], XOR-swizzled (R12)
    __shared__ __align__(16) ushort_t Pw[4 * 512];    // per-wave 16x32, swizzled
    const int h = blockIdx.x, b = blockIdx.y;
    const int tid = threadIdx.x, wid = tid >> 6, lane = tid & 63;
    const size_t baseq = (size_t)(b * S_) * 2304 + h * 64;
    char* const vtb = (char*)Vt;

    {
        const int jr  = tid >> 3;          // 0..31 (V path)
        const int dh0 = (tid & 7) * 8;
        const int jk  = wid * 8 + (lane >> 3);   // K path: row within pass
        #pragma unroll
        for (int pass = 0; pass < 7; ++pass) {
            const int j  = pass * 32 + jk;
            const int cs = (lane & 7) ^ (j & 7);
            GLOAD_LDS16(qkv + baseq + (size_t)j * 2304 + 768 + cs * 8,
                        (char*)Ks + (pass * 32 + wid * 8) * 128);
            const int j2 = pass * 32 + jr;
            bf16x8 vv = *(const bf16x8*)&qkv[baseq + (size_t)j2 * 2304 + 1536 + dh0];
            #pragma unroll
            for (int i = 0; i < 8; ++i)
                *(ushort_t*)(vtb + ((((dh0 + i) * VLD + j2) * 2) ^ ((tid & 7) << 4))) = (ushort_t)vv[i];
        }
    }
    __syncthreads();   // full vmcnt/lgkm drain covers the K DMA + V writes

    char* const pwb = (char*)Pw + wid * 1024;

    for (int it = 0; it < 4; ++it) {
        int sq = it * 64 + wid * 16 + (lane & 15);
        const int sqc = (sq < S_) ? sq : (S_ - 1);
        bf16x8 qf[2];
        #pragma unroll
        for (int kk = 0; kk < 2; ++kk)
            qf[kk] = *(const bf16x8*)&qkv[baseq + (size_t)sqc * 2304 + kk * 32 + (lane >> 4) * 8];

        f32x4 sa[14];
        #pragma unroll
        for (int nf = 0; nf < 14; ++nf) sa[nf] = (f32x4){0.f, 0.f, 0.f, 0.f};
        #pragma unroll
        for (int kk = 0; kk < 2; ++kk) {
            #pragma unroll
            for (int nf = 0; nf < 14; ++nf) {
                const int j = nf * 16 + (lane & 15);
                const int off = (j * 128 + kk * 64 + (lane >> 4) * 16) ^ ((j & 7) << 4);
                bf16x8 kf = *(const bf16x8*)((const char*)Ks + off);
                sa[nf] = __builtin_amdgcn_mfma_f32_16x16x32_bf16(qf[kk], kf, sa[nf], 0, 0, 0);
            }
        }

        const int jcol = lane & 15;
        float mx[4] = {-1e30f, -1e30f, -1e30f, -1e30f};
        #pragma unroll
        for (int nf = 0; nf < 14; ++nf)
            #pragma unroll
            for (int r = 0; r < 4; ++r) mx[r] = fmaxf(mx[r], sa[nf][r]);
        float ls[4];
        #pragma unroll
        for (int r = 0; r < 4; ++r) {
            float m = mx[r] * 0.125f;
            m = fmaxf(m, __shfl_xor(m, 1, 64));
            m = fmaxf(m, __shfl_xor(m, 2, 64));
            m = fmaxf(m, __shfl_xor(m, 4, 64));
            m = fmaxf(m, __shfl_xor(m, 8, 64));
            float s = 0.f;
            #pragma unroll
            for (int nf = 0; nf < 14; ++nf) {
                const int j = nf * 16 + jcol;
                float p = (j < S_) ? exp2f((sa[nf][r] * 0.125f - m) * 1.44269504088896f) : 0.f;
                sa[nf][r] = p;
                s += p;
            }
            s += __shfl_xor(s, 1, 64);
            s += __shfl_xor(s, 2, 64);
            s += __shfl_xor(s, 4, 64);
            s += __shfl_xor(s, 8, 64);
            ls[r] = s;
        }

        f32x4 oa[4];
        #pragma unroll
        for (int nf = 0; nf < 4; ++nf) oa[nf] = (f32x4){0.f, 0.f, 0.f, 0.f};
        #pragma unroll
        for (int kt = 0; kt < 7; ++kt) {
            #pragma unroll
            for (int half = 0; half < 2; ++half) {
                #pragma unroll
                for (int r = 0; r < 4; ++r) {
                    const int qr = (lane >> 4) * 4 + r;
                    const int jl = half * 16 + jcol;
                    const int off = (qr * 64 + jl * 2) ^ (((qr >> 1) & 3) << 4);
                    *(ushort_t*)(pwb + off) = f2bf(sa[kt * 2 + half][r]);
                }
            }
            const int arow = lane & 15;
            const int aoff2 = (arow * 64 + (lane >> 4) * 16) ^ (((arow >> 1) & 3) << 4);
            bf16x8 pa = *(const bf16x8*)(pwb + aoff2);
            #pragma unroll
            for (int nf = 0; nf < 4; ++nf) {
                const int dh = nf * 16 + (lane & 15);
                const int voff = ((dh * VLD + kt * 32 + (lane >> 4) * 8) * 2) ^ ((((nf * 2) + ((lane & 15) >> 3)) & 7) << 4);
                bf16x8 vb = *(const bf16x8*)(vtb + voff);
                oa[nf] = __builtin_amdgcn_mfma_f32_16x16x32_bf16(pa, vb, oa[nf], 0, 0, 0);
            }
        }

        #pragma unroll
        for (int r = 0; r < 4; ++r) {
            const int so = it * 64 + wid * 16 + (lane >> 4) * 4 + r;
            if (so < S_) {
                const float inv = 1.0f / ls[r];
                #pragma unroll
                for (int nf = 0; nf < 4; ++nf)
                    o[(size_t)(b * S_ + so) * 768 + h * 64 + nf * 16 + (lane & 15)] = f2bf(oa[nf][r] * inv);
            }
        }
    }
}

// ====================== small kernels ======================
__global__ __launch_bounds__(256)
void tcast_k(const float* __restrict__ in, ushort_t* __restrict__ out,
             int R, int C, size_t in_ls, size_t out_ls) {
    __shared__ float t[32][33];
    const float* ip = in + (size_t)blockIdx.z * in_ls;
    ushort_t* op = out + (size_t)blockIdx.z * out_ls;
    const int c0 = blockIdx.x * 32, r0 = blockIdx.y * 32;
    const int tx = threadIdx.x & 31, ty = threadIdx.x >> 5;
    #pragma unroll
    for (int i = 0; i < 4; ++i)
        t[ty + i * 8][tx] = ip[(size_t)(r0 + ty + i * 8) * C + c0 + tx];
    __syncthreads();
    #pragma unroll
    for (int i = 0; i < 4; ++i)
        op[(size_t)(c0 + ty + i * 8) * R + r0 + tx] = f2bf(t[tx][ty + i * 8]);
}

__global__ void cast_k(const float* __restrict__ in, ushort_t* __restrict__ out, int n) {
    int i = blockIdx.x * 256 + threadIdx.x;
    if (i < n) out[i] = f2bf(in[i]);
}

__global__ void biascat_k(const float* __restrict__ qb, const float* __restrict__ kb,
                          const float* __restrict__ vb, float* __restrict__ out) {
    int i = blockIdx.x * 256 + threadIdx.x;       // l*2304 + n
    if (i >= DEPTH_ * 2304) return;
    int l = i / 2304, n = i % 2304;
    float v = (n < 768) ? qb[l * 768 + n] : (n < 1536) ? kb[l * 768 + n - 768] : vb[l * 768 + n - 1536];
    out[i] = v;
}

__global__ void im2col_k(const float* __restrict__ x, ushort_t* __restrict__ pm) {
    size_t idx = (size_t)blockIdx.x * 256 + threadIdx.x;
    if (idx >= (size_t)MP_ * 768) return;
    int col = (int)(idx % 768);
    int row = (int)(idx / 768);
    int b = row / NP_, p = row % NP_;
    int c = col >> 8, rem = col & 255, ky = rem >> 4, kx = rem & 15;
    int py = p / 14, px = p % 14;
    pm[idx] = f2bf(x[(((size_t)b * 3 + c) * 224 + (py * 16 + ky)) * 224 + (px * 16 + kx)]);
}

__global__ void assemble_k(const float* __restrict__ pe, const float* __restrict__ cls,
                           const float* __restrict__ pos, float* __restrict__ h) {
    size_t idx = (size_t)blockIdx.x * 256 + threadIdx.x;
    if (idx >= (size_t)M_ * D_) return;
    int d = (int)(idx % D_);
    int row = (int)(idx / D_);
    int b = row / S_, s = row % S_;
    float v;
    if (s == 0) v = cls[d] + pos[d];
    else        v = pe[((size_t)b * NP_ + (s - 1)) * D_ + d] + pos[(size_t)s * D_ + d];
    h[idx] = v;
}

// ======= vectorized LayerNorm: 4 rows/block, one wave per row (R15) =======
template<bool BF16OUT>
__global__ __launch_bounds__(256)
void ln4_k(const float* __restrict__ x, size_t xstride,
           void* __restrict__ y, size_t ystride,
           const float* __restrict__ s, const float* __restrict__ b, int nrows) {
    const int wid = threadIdx.x >> 6, lane = threadIdx.x & 63;
    const int row = blockIdx.x * 4 + wid;
    if (row >= nrows) return;
    const float* xr = x + (size_t)row * xstride;

    f32x4 v[3];
    float sum = 0.f;
    #pragma unroll
    for (int t = 0; t < 3; ++t) {
        v[t] = *(const f32x4*)&xr[lane * 4 + t * 256];
        sum += (v[t][0] + v[t][1]) + (v[t][2] + v[t][3]);
    }
    #pragma unroll
    for (int off = 32; off > 0; off >>= 1) sum += __shfl_xor(sum, off, 64);
    const float mu = sum * (1.0f / 768.0f);

    float vs = 0.f;
    #pragma unroll
    for (int t = 0; t < 3; ++t)
        #pragma unroll
        for (int e = 0; e < 4; ++e) { float d = v[t][e] - mu; vs += d * d; }
    #pragma unroll
    for (int off = 32; off > 0; off >>= 1) vs += __shfl_xor(vs, off, 64);
    const float rstd = rsqrtf(vs * (1.0f / 768.0f) + 1e-6f);

    #pragma unroll
    for (int t = 0; t < 3; ++t) {
        const int c = lane * 4 + t * 256;
        const f32x4 sv = *(const f32x4*)&s[c];
        const f32x4 bv = *(const f32x4*)&b[c];
        if (BF16OUT) {
            short4_t o4;
            #pragma unroll
            for (int e = 0; e < 4; ++e)
                o4[e] = (short)f2bf((v[t][e] - mu) * rstd * sv[e] + bv[e]);
            *(short4_t*)((ushort_t*)y + (size_t)row * ystride + c) = o4;
        } else {
            f32x4 o;
            #pragma unroll
            for (int e = 0; e < 4; ++e)
                o[e] = (v[t][e] - mu) * rstd * sv[e] + bv[e];
            *(f32x4*)((float*)y + (size_t)row * ystride + c) = o;
        }
    }
}

// ====================== launch ======================
extern "C" void kernel_launch(void* const* d_in, const int* in_sizes, int n_in,
                              void* d_out, int out_size, void* d_ws, size_t ws_size,
                              hipStream_t stream) {
    const float* x       = (const float*)d_in[0];
    const float* patch_w = (const float*)d_in[1];
    const float* patch_b = (const float*)d_in[2];
    const float* cls_tok = (const float*)d_in[3];
    const float* pos_emb = (const float*)d_in[4];
    const float* ln1_s   = (const float*)d_in[5];
    const float* ln1_b   = (const float*)d_in[6];
    const float* qw      = (const float*)d_in[7];
    const float* qb      = (const float*)d_in[8];
    const float* kw      = (const float*)d_in[9];
    const float* kb      = (const float*)d_in[10];
    const float* vw      = (const float*)d_in[11];
    const float* vb      = (const float*)d_in[12];
    const float* pw      = (const float*)d_in[13];
    const float* pb      = (const float*)d_in[14];
    const float* ln2_s   = (const float*)d_in[15];
    const float* ln2_b   = (const float*)d_in[16];
    const float* fc1_w   = (const float*)d_in[17];
    const float* fc1_b   = (const float*)d_in[18];
    const float* fc2_w   = (const float*)d_in[19];
    const float* fc2_b   = (const float*)d_in[20];
    const float* lnf_s   = (const float*)d_in[21];
    const float* lnf_b   = (const float*)d_in[22];
    float* out = (float*)d_out;

    // ---- workspace layout (bytes) ----
    char* ws = (char*)d_ws;
    float*    h      = (float*)ws;                                   // MR*768 f32
    ushort_t* yb     = (ushort_t*)(ws + 39321600);                   // MR*768 bf16
    char*     Ubase  = ws + 58982400;                                 // shared region (MR*3072 bf16 max)
    ushort_t* qkvb   = (ushort_t*)Ubase;                              // MR*2304 bf16
    ushort_t* ub     = (ushort_t*)Ubase;                              // MR*3072 bf16
    float*    peb    = (float*)Ubase;                                 // MR*768 f32 (prologue)
    ushort_t* wqkv_t = (ushort_t*)(ws + 137625600);                   // 12*2304*768
    ushort_t* wp_t   = (ushort_t*)(ws + 180092928);                   // 12*768*768
    ushort_t* w1_t   = (ushort_t*)(ws + 194248704);                   // 12*3072*768
    ushort_t* w2_t   = (ushort_t*)(ws + 250871808);                   // 12*768*3072
    ushort_t* pwt    = (ushort_t*)(ws + 307494912);                   // 768*768
    float*    bqkv   = (float*)(ws + 308674560);                      // 12*2304 f32

    const dim3 blk(256);
    const dim3 blk512(512);

    // ---- weight prep ----
    tcast_k<<<dim3(768 / 32, 768 / 32, 12), blk, 0, stream>>>(qw, wqkv_t,            768, 768, (size_t)768 * 768, (size_t)2304 * 768);
    tcast_k<<<dim3(768 / 32, 768 / 32, 12), blk, 0, stream>>>(kw, wqkv_t + 768 * 768, 768, 768, (size_t)768 * 768, (size_t)2304 * 768);
    tcast_k<<<dim3(768 / 32, 768 / 32, 12), blk, 0, stream>>>(vw, wqkv_t + 1536 * 768, 768, 768, (size_t)768 * 768, (size_t)2304 * 768);
    tcast_k<<<dim3(768 / 32, 768 / 32, 12), blk, 0, stream>>>(pw, wp_t, 768, 768, (size_t)768 * 768, (size_t)768 * 768);
    tcast_k<<<dim3(3072 / 32, 768 / 32, 12), blk, 0, stream>>>(fc1_w, w1_t, 768, 3072, (size_t)768 * 3072, (size_t)3072 * 768);
    tcast_k<<<dim3(768 / 32, 3072 / 32, 12), blk, 0, stream>>>(fc2_w, w2_t, 3072, 768, (size_t)3072 * 768, (size_t)768 * 3072);
    cast_k<<<dim3((768 * 768 + 255) / 256), blk, 0, stream>>>(patch_w, pwt, 768 * 768);
    biascat_k<<<dim3((DEPTH_ * 2304 + 255) / 256), blk, 0, stream>>>(qb, kb, vb, bqkv);

    // ---- patch embed ----
    im2col_k<<<dim3(((size_t)MP_ * 768 + 255) / 256), blk, 0, stream>>>(x, yb);
    mm_t<3, 128, 4><<<dim3(6, 100), blk, 0, stream>>>(yb, pwt, patch_b, nullptr, peb, MR, 768, 768);
    assemble_k<<<dim3(((size_t)M_ * D_ + 255) / 256), blk, 0, stream>>>(peb, cls_tok, pos_emb, h);

    // ---- transformer blocks ----
    for (int l = 0; l < DEPTH_; ++l) {
        const size_t oDD = (size_t)l * 768 * 768;
        const size_t oD  = (size_t)l * 768;
        const size_t oDF = (size_t)l * 768 * FF_;
        const size_t oF  = (size_t)l * FF_;

        ln4_k<true><<<dim3(M_ / 4), blk, 0, stream>>>(h, 768, yb, 768, ln1_s + oD, ln1_b + oD, M_);
        mm_t<0, 256, 8><<<dim3(9, 100), blk512, 0, stream>>>(yb, wqkv_t + (size_t)l * 2304 * 768, bqkv + (size_t)l * 2304, nullptr, qkvb, MR, 2304, 768);
        attn2_k<<<dim3(H_, B_), blk, 0, stream>>>(qkvb, yb);
        mm_t<2, 128, 4><<<dim3(6, 100), blk, 0, stream>>>(yb, wp_t + oDD, pb + oD, h, h, MR, 768, 768);
        ln4_k<true><<<dim3(M_ / 4), blk, 0, stream>>>(h, 768, yb, 768, ln2_s + oD, ln2_b + oD, M_);
        mm_t<1, 256, 8><<<dim3(12, 100), blk512, 0, stream>>>(yb, w1_t + oDF, fc1_b + oF, nullptr, ub, MR, FF_, 768);
        mm_t<2, 128, 4><<<dim3(6, 100), blk, 0, stream>>>(ub, w2_t + oDF, fc2_b + oD, h, h, MR, 768, FF_);
    }

    // ---- final LN on CLS rows ----
    ln4_k<false><<<dim3(B_ / 4), blk, 0, stream>>>(h, (size_t)S_ * D_, out, 768, lnf_s, lnf_b, B_);
}